// Round 4
// baseline (187.432 us; speedup 1.0000x reference)
//
#include <hip/hip_runtime.h>
#include <cstdint>
#include <cstddef>

static constexpr int C = 256;
static constexpr int N = 1024;
static constexpr int M = 4;                         // T*B
static constexpr size_t PLANE = (size_t)M * C * N;  // 1M elements per branch

// ---------------------------------------------------------------------------
// fp64 GEMM: H[m][o][n] = sum_c W[o][c] * X[m][c][n].
// Block tile 16 o x 256 n; thread = one n, all 16 o (acc[16]).
// Weights: fp32 -> fp64 LDS once per block (32 KB), wave-uniform broadcast
// reads in the hot loop. X: coalesced dword loads.
// grid = (4 n-tiles, 16 o-strips, 12 planes br*4+m), 256 threads.
// ---------------------------------------------------------------------------
__global__ __launch_bounds__(256) void gemm_qkv(
    const float* __restrict__ x, const float* __restrict__ y,
    const float* __restrict__ Wq, const float* __restrict__ Wk,
    const float* __restrict__ Wv, double* __restrict__ hbase)
{
    const int bz = blockIdx.z;
    const int br = bz >> 2, m = bz & 3;
    const float* __restrict__ W = (br == 0) ? Wq : (br == 1) ? Wk : Wv;
    const float* __restrict__ X = ((br == 0) ? x : y) + (size_t)m * C * N;
    double* __restrict__ H = hbase + (size_t)br * PLANE + (size_t)m * C * N;

    const int o0  = blockIdx.y * 16;
    const int tid = threadIdx.x;
    const int n   = blockIdx.x * 256 + tid;

    __shared__ double Ws[16 * 256];          // [o][k], 32 KB
    #pragma unroll
    for (int j = 0; j < 16; ++j) {
        int l = j * 256 + tid;               // o = l>>8, k = l&255
        Ws[l] = (double)W[(size_t)(o0 + (l >> 8)) * C + (l & 255)];
    }
    __syncthreads();

    double acc[16];
    #pragma unroll
    for (int i = 0; i < 16; ++i) acc[i] = 0.0;

    const float* __restrict__ Xn = X + n;

    for (int k = 0; k < C; k += 8) {
        double xv[8];
        #pragma unroll
        for (int j = 0; j < 8; ++j)
            xv[j] = (double)Xn[(size_t)(k + j) * N];
        #pragma unroll
        for (int i = 0; i < 16; ++i) {
            const double* __restrict__ wr = &Ws[i * 256 + k];
            #pragma unroll
            for (int j = 0; j < 8; ++j)
                acc[i] = fma(wr[j], xv[j], acc[i]);
        }
    }
    #pragma unroll
    for (int i = 0; i < 16; ++i)
        H[(size_t)(o0 + i) * N + n] = acc[i];
}

// Proj GEMM: 8 o x 256 n block tile (more waves for latency hiding at small
// total work), binary uint8 X. grid = (4 n-tiles, 32 o-strips, 4 planes).
__global__ __launch_bounds__(256) void gemm_p(
    const unsigned char* __restrict__ s2, const float* __restrict__ Wp,
    double* __restrict__ hp)
{
    const int m = blockIdx.z;
    const unsigned char* __restrict__ X = s2 + (size_t)m * C * N;
    double* __restrict__ H = hp + (size_t)m * C * N;

    const int o0  = blockIdx.y * 8;
    const int tid = threadIdx.x;
    const int n   = blockIdx.x * 256 + tid;

    __shared__ double Ws[8 * 256];           // 16 KB
    #pragma unroll
    for (int j = 0; j < 8; ++j) {
        int l = j * 256 + tid;               // o = l>>8, k = l&255
        Ws[l] = (double)Wp[(size_t)(o0 + (l >> 8)) * C + (l & 255)];
    }
    __syncthreads();

    double acc[8];
    #pragma unroll
    for (int i = 0; i < 8; ++i) acc[i] = 0.0;

    const unsigned char* __restrict__ Xn = X + n;

    for (int k = 0; k < C; k += 8) {
        double xv[8];
        #pragma unroll
        for (int j = 0; j < 8; ++j)
            xv[j] = (double)(int)Xn[(size_t)(k + j) * N];
        #pragma unroll
        for (int i = 0; i < 8; ++i) {
            const double* __restrict__ wr = &Ws[i * 256 + k];
            #pragma unroll
            for (int j = 0; j < 8; ++j)
                acc[i] = fma(wr[j], xv[j], acc[i]);
        }
    }
    #pragma unroll
    for (int i = 0; i < 8; ++i)
        H[(size_t)(o0 + i) * N + n] = acc[i];
}

// ---------------------------------------------------------------------------
// Fused BN stats + spike for q/k/v. Block = (channel o, branch br).
// Values held in registers: single read of h. Writes 0/1 bytes.
// ---------------------------------------------------------------------------
__global__ __launch_bounds__(256) void bnspike_qkv(
    const double* __restrict__ hbase,
    const float* __restrict__ gq, const float* __restrict__ bq,
    const float* __restrict__ gk, const float* __restrict__ bk,
    const float* __restrict__ gv, const float* __restrict__ bv,
    unsigned char* __restrict__ sbase)
{
    const int o  = blockIdx.x;
    const int br = blockIdx.y;
    const double* __restrict__ h = hbase + (size_t)br * PLANE + (size_t)o * N;
    const int tid = threadIdx.x;

    double v[16];
    double s = 0.0, ss = 0.0;
    #pragma unroll
    for (int j = 0; j < 16; ++j) {
        int l  = j * 256 + tid;             // 0..4095
        int mm = l >> 10, nn = l & 1023;
        v[j] = h[(size_t)mm * C * N + nn];
        s += v[j]; ss += v[j] * v[j];
    }
    #pragma unroll
    for (int off = 32; off > 0; off >>= 1) {
        s  += __shfl_down(s, off, 64);
        ss += __shfl_down(ss, off, 64);
    }
    __shared__ double rs[4], rss[4], sstat[2];
    const int lane = tid & 63, wv_ = tid >> 6;
    if (lane == 0) { rs[wv_] = s; rss[wv_] = ss; }
    __syncthreads();
    if (tid == 0) {
        double S  = rs[0] + rs[1] + rs[2] + rs[3];
        double SS = rss[0] + rss[1] + rss[2] + rss[3];
        double mean = S / 4096.0;
        double var  = SS / 4096.0 - mean * mean;
        sstat[0] = mean;
        sstat[1] = 1.0 / sqrt(var + 1e-5);
    }
    __syncthreads();
    const double mean = sstat[0], inv = sstat[1];
    const float* g = (br == 0) ? gq : (br == 1) ? gk : gv;
    const float* b = (br == 0) ? bq : (br == 1) ? bk : bv;
    const double gc = (double)g[o], bc = (double)b[o];
    unsigned char* out = sbase + (size_t)br * PLANE + (size_t)o * N;
    #pragma unroll
    for (int j = 0; j < 16; ++j) {
        int l  = j * 256 + tid;
        int mm = l >> 10, nn = l & 1023;
        double t = gc * (v[j] - mean) * inv + bc;
        out[(size_t)mm * C * N + nn] = (t >= 1.0) ? (unsigned char)1 : (unsigned char)0;
    }
}

// ---------------------------------------------------------------------------
// Fused attention: kTv (popc over packed 0/1 bytes) + S = q . kTv, spike S>=2
// (== SCALE*S >= 0.5 with exact integers). grid = (4 n-chunks, 16 heads, 4 t).
// ---------------------------------------------------------------------------
__global__ __launch_bounds__(256) void attn_kernel(
    const unsigned char* __restrict__ qb, const unsigned char* __restrict__ kb,
    const unsigned char* __restrict__ vb, unsigned char* __restrict__ s2)
{
    const int nc = blockIdx.x;
    const int hh = blockIdx.y;
    const int t  = blockIdx.z;
    const int tid = threadIdx.x;

    __shared__ unsigned int kw[16][257];
    __shared__ unsigned int vw[16][257];
    __shared__ int kt[256];

    #pragma unroll
    for (int j = 0; j < 4; ++j) {
        int idx = j * 256 + tid;            // 0..1023 -> 16 rows x 64 uint4
        int r = idx >> 6, q4 = idx & 63;
        size_t goff = ((size_t)(t * C + hh * 16 + r)) * N + (size_t)q4 * 16;
        uint4 kk = *(const uint4*)(kb + goff);
        uint4 vv = *(const uint4*)(vb + goff);
        kw[r][q4 * 4 + 0] = kk.x; kw[r][q4 * 4 + 1] = kk.y;
        kw[r][q4 * 4 + 2] = kk.z; kw[r][q4 * 4 + 3] = kk.w;
        vw[r][q4 * 4 + 0] = vv.x; vw[r][q4 * 4 + 1] = vv.y;
        vw[r][q4 * 4 + 2] = vv.z; vw[r][q4 * 4 + 3] = vv.w;
    }
    __syncthreads();

    const int d = tid >> 4, dp = tid & 15;
    int sum = 0;
    #pragma unroll 8
    for (int wd = 0; wd < 256; ++wd)
        sum += __popc(kw[d][wd] & vw[dp][wd]);
    kt[tid] = sum;                          // kt[d*16+dp], exact integer
    __syncthreads();

    const int n = nc * 256 + tid;
    int sums[16];
    #pragma unroll
    for (int i = 0; i < 16; ++i) sums[i] = 0;
    #pragma unroll
    for (int d2 = 0; d2 < 16; ++d2) {
        int qv = (int)qb[((size_t)(t * C + hh * 16 + d2)) * N + n];
        #pragma unroll
        for (int dp2 = 0; dp2 < 16; ++dp2)
            sums[dp2] += qv * kt[d2 * 16 + dp2];
    }
    #pragma unroll
    for (int dp2 = 0; dp2 < 16; ++dp2)
        s2[((size_t)(t * C + hh * 16 + dp2)) * N + n] = (sums[dp2] >= 2) ? 1 : 0;
}

// ---------------------------------------------------------------------------
// Fused BN stats + spike for proj -> fp32 0/1 output. grid = (256)
// ---------------------------------------------------------------------------
__global__ __launch_bounds__(256) void bnspike_p(
    const double* __restrict__ hp,
    const float* __restrict__ gp, const float* __restrict__ bp,
    float* __restrict__ outp)
{
    const int o = blockIdx.x;
    const double* __restrict__ h = hp + (size_t)o * N;
    const int tid = threadIdx.x;

    double v[16];
    double s = 0.0, ss = 0.0;
    #pragma unroll
    for (int j = 0; j < 16; ++j) {
        int l  = j * 256 + tid;
        int mm = l >> 10, nn = l & 1023;
        v[j] = h[(size_t)mm * C * N + nn];
        s += v[j]; ss += v[j] * v[j];
    }
    #pragma unroll
    for (int off = 32; off > 0; off >>= 1) {
        s  += __shfl_down(s, off, 64);
        ss += __shfl_down(ss, off, 64);
    }
    __shared__ double rs[4], rss[4], sstat[2];
    const int lane = tid & 63, wv_ = tid >> 6;
    if (lane == 0) { rs[wv_] = s; rss[wv_] = ss; }
    __syncthreads();
    if (tid == 0) {
        double S  = rs[0] + rs[1] + rs[2] + rs[3];
        double SS = rss[0] + rss[1] + rss[2] + rss[3];
        double mean = S / 4096.0;
        double var  = SS / 4096.0 - mean * mean;
        sstat[0] = mean;
        sstat[1] = 1.0 / sqrt(var + 1e-5);
    }
    __syncthreads();
    const double mean = sstat[0], inv = sstat[1];
    const double gc = (double)gp[o], bc = (double)bp[o];
    float* out = outp + (size_t)o * N;
    #pragma unroll
    for (int j = 0; j < 16; ++j) {
        int l  = j * 256 + tid;
        int mm = l >> 10, nn = l & 1023;
        double t = gc * (v[j] - mean) * inv + bc;
        out[(size_t)mm * C * N + nn] = (t >= 1.0) ? 1.0f : 0.0f;
    }
}

// ---------------------------------------------------------------------------
extern "C" void kernel_launch(void* const* d_in, const int* in_sizes, int n_in,
                              void* d_out, int out_size, void* d_ws, size_t ws_size,
                              hipStream_t stream)
{
    const float* x  = (const float*)d_in[0];
    const float* y  = (const float*)d_in[1];
    const float* Wq = (const float*)d_in[2];
    const float* gq = (const float*)d_in[3];
    const float* bq = (const float*)d_in[4];
    const float* Wk = (const float*)d_in[5];
    const float* gk = (const float*)d_in[6];
    const float* bk = (const float*)d_in[7];
    const float* Wv = (const float*)d_in[8];
    const float* gv = (const float*)d_in[9];
    const float* bv = (const float*)d_in[10];
    const float* Wp = (const float*)d_in[11];
    const float* gp = (const float*)d_in[12];
    const float* bp = (const float*)d_in[13];
    float* out = (float*)d_out;

    // Workspace layout (28 MB total):
    //   [0, 24MB)  hq (3 branches fp64); hp (4 planes fp64) aliases [0,8MB)
    //   [24, 28MB) qb/kb/vb/s2b binary bytes
    char* ws = (char*)d_ws;
    double* hq = (double*)ws;
    double* hp = hq;                                      // alias: hq dead by then
    unsigned char* qb  = (unsigned char*)(ws + 3 * PLANE * sizeof(double));
    unsigned char* kb2 = qb + PLANE;
    unsigned char* vb2 = qb + 2 * PLANE;
    unsigned char* s2b = qb + 3 * PLANE;

    gemm_qkv<<<dim3(4, 16, 12), 256, 0, stream>>>(x, y, Wq, Wk, Wv, hq);
    bnspike_qkv<<<dim3(256, 3), 256, 0, stream>>>(hq, gq, bq, gk, bk, gv, bv, qb);
    attn_kernel<<<dim3(4, 16, 4), 256, 0, stream>>>(qb, kb2, vb2, s2b);
    gemm_p<<<dim3(4, 32, 4), 256, 0, stream>>>(s2b, Wp, hp);
    bnspike_p<<<dim3(256), 256, 0, stream>>>(hp, gp, bp, out);
}

// Round 5
// 183.368 us; speedup vs baseline: 1.0222x; 1.0222x over previous
//
#include <hip/hip_runtime.h>
#include <cstdint>
#include <cstddef>

static constexpr int C = 256;
static constexpr int N = 1024;
static constexpr int M = 4;                         // T*B
static constexpr size_t PLANE = (size_t)M * C * N;  // 1M elements per branch

// ---------------------------------------------------------------------------
// fp64 GEMM: H[m][o][n] = sum_c W[o][c] * X[m][c][n].
// Block tile 16 o x 256 n; thread = one n, all 16 o (acc[16]).
// Weights: fp32 -> fp64 LDS once per block (32 KB); hot loop reads them as
// double2 (ds_read_b128, wave-uniform broadcast => conflict-free, halves the
// LDS instruction count vs b64). X: coalesced dword loads with one-chunk
// register prefetch so VMEM latency overlaps the FMA block.
// grid = (4 n-tiles, 16 o-strips, 12 planes br*4+m), 256 threads.
// ---------------------------------------------------------------------------
__global__ __launch_bounds__(256) void gemm_qkv(
    const float* __restrict__ x, const float* __restrict__ y,
    const float* __restrict__ Wq, const float* __restrict__ Wk,
    const float* __restrict__ Wv, double* __restrict__ hbase)
{
    const int bz = blockIdx.z;
    const int br = bz >> 2, m = bz & 3;
    const float* __restrict__ W = (br == 0) ? Wq : (br == 1) ? Wk : Wv;
    const float* __restrict__ X = ((br == 0) ? x : y) + (size_t)m * C * N;
    double* __restrict__ H = hbase + (size_t)br * PLANE + (size_t)m * C * N;

    const int o0  = blockIdx.y * 16;
    const int tid = threadIdx.x;
    const int n   = blockIdx.x * 256 + tid;

    __shared__ __align__(16) double Ws[16 * 256];    // [o][k], 32 KB
    #pragma unroll
    for (int j = 0; j < 16; ++j) {
        int l = j * 256 + tid;                       // o = l>>8, k = l&255
        Ws[l] = (double)W[(size_t)(o0 + (l >> 8)) * C + (l & 255)];
    }
    __syncthreads();

    double acc[16];
    #pragma unroll
    for (int i = 0; i < 16; ++i) acc[i] = 0.0;

    const float* __restrict__ Xn = X + n;

    float xf[8];
    #pragma unroll
    for (int j = 0; j < 8; ++j) xf[j] = Xn[(size_t)j * N];

    for (int k = 0; k < C; k += 8) {
        double xv[8];
        #pragma unroll
        for (int j = 0; j < 8; ++j) xv[j] = (double)xf[j];
        if (k + 8 < C) {
            #pragma unroll
            for (int j = 0; j < 8; ++j) xf[j] = Xn[(size_t)(k + 8 + j) * N];
        }
        #pragma unroll
        for (int i = 0; i < 16; ++i) {
            const double2* __restrict__ wr = (const double2*)(Ws + i * 256 + k);
            double2 w0 = wr[0], w1 = wr[1], w2 = wr[2], w3 = wr[3];
            acc[i] = fma(w0.x, xv[0], acc[i]);
            acc[i] = fma(w0.y, xv[1], acc[i]);
            acc[i] = fma(w1.x, xv[2], acc[i]);
            acc[i] = fma(w1.y, xv[3], acc[i]);
            acc[i] = fma(w2.x, xv[4], acc[i]);
            acc[i] = fma(w2.y, xv[5], acc[i]);
            acc[i] = fma(w3.x, xv[6], acc[i]);
            acc[i] = fma(w3.y, xv[7], acc[i]);
        }
    }
    #pragma unroll
    for (int i = 0; i < 16; ++i)
        H[(size_t)(o0 + i) * N + n] = acc[i];
}

// Proj GEMM: 8 o x 256 n block tile, binary uint8 X, same b128+prefetch
// structure. grid = (4 n-tiles, 32 o-strips, 4 planes).
__global__ __launch_bounds__(256) void gemm_p(
    const unsigned char* __restrict__ s2, const float* __restrict__ Wp,
    double* __restrict__ hp)
{
    const int m = blockIdx.z;
    const unsigned char* __restrict__ X = s2 + (size_t)m * C * N;
    double* __restrict__ H = hp + (size_t)m * C * N;

    const int o0  = blockIdx.y * 8;
    const int tid = threadIdx.x;
    const int n   = blockIdx.x * 256 + tid;

    __shared__ __align__(16) double Ws[8 * 256];     // 16 KB
    #pragma unroll
    for (int j = 0; j < 8; ++j) {
        int l = j * 256 + tid;                       // o = l>>8, k = l&255
        Ws[l] = (double)Wp[(size_t)(o0 + (l >> 8)) * C + (l & 255)];
    }
    __syncthreads();

    double acc[8];
    #pragma unroll
    for (int i = 0; i < 8; ++i) acc[i] = 0.0;

    const unsigned char* __restrict__ Xn = X + n;

    unsigned char xb[8];
    #pragma unroll
    for (int j = 0; j < 8; ++j) xb[j] = Xn[(size_t)j * N];

    for (int k = 0; k < C; k += 8) {
        double xv[8];
        #pragma unroll
        for (int j = 0; j < 8; ++j) xv[j] = (double)(int)xb[j];
        if (k + 8 < C) {
            #pragma unroll
            for (int j = 0; j < 8; ++j) xb[j] = Xn[(size_t)(k + 8 + j) * N];
        }
        #pragma unroll
        for (int i = 0; i < 8; ++i) {
            const double2* __restrict__ wr = (const double2*)(Ws + i * 256 + k);
            double2 w0 = wr[0], w1 = wr[1], w2 = wr[2], w3 = wr[3];
            acc[i] = fma(w0.x, xv[0], acc[i]);
            acc[i] = fma(w0.y, xv[1], acc[i]);
            acc[i] = fma(w1.x, xv[2], acc[i]);
            acc[i] = fma(w1.y, xv[3], acc[i]);
            acc[i] = fma(w2.x, xv[4], acc[i]);
            acc[i] = fma(w2.y, xv[5], acc[i]);
            acc[i] = fma(w3.x, xv[6], acc[i]);
            acc[i] = fma(w3.y, xv[7], acc[i]);
        }
    }
    #pragma unroll
    for (int i = 0; i < 8; ++i)
        H[(size_t)(o0 + i) * N + n] = acc[i];
}

// ---------------------------------------------------------------------------
// Fused BN stats + spike for q/k/v. Block = (channel o, branch br).
// Values held in registers: single read of h. Writes 0/1 bytes.
// ---------------------------------------------------------------------------
__global__ __launch_bounds__(256) void bnspike_qkv(
    const double* __restrict__ hbase,
    const float* __restrict__ gq, const float* __restrict__ bq,
    const float* __restrict__ gk, const float* __restrict__ bk,
    const float* __restrict__ gv, const float* __restrict__ bv,
    unsigned char* __restrict__ sbase)
{
    const int o  = blockIdx.x;
    const int br = blockIdx.y;
    const double* __restrict__ h = hbase + (size_t)br * PLANE + (size_t)o * N;
    const int tid = threadIdx.x;

    double v[16];
    double s = 0.0, ss = 0.0;
    #pragma unroll
    for (int j = 0; j < 16; ++j) {
        int l  = j * 256 + tid;             // 0..4095
        int mm = l >> 10, nn = l & 1023;
        v[j] = h[(size_t)mm * C * N + nn];
        s += v[j]; ss += v[j] * v[j];
    }
    #pragma unroll
    for (int off = 32; off > 0; off >>= 1) {
        s  += __shfl_down(s, off, 64);
        ss += __shfl_down(ss, off, 64);
    }
    __shared__ double rs[4], rss[4], sstat[2];
    const int lane = tid & 63, wv_ = tid >> 6;
    if (lane == 0) { rs[wv_] = s; rss[wv_] = ss; }
    __syncthreads();
    if (tid == 0) {
        double S  = rs[0] + rs[1] + rs[2] + rs[3];
        double SS = rss[0] + rss[1] + rss[2] + rss[3];
        double mean = S / 4096.0;
        double var  = SS / 4096.0 - mean * mean;
        sstat[0] = mean;
        sstat[1] = 1.0 / sqrt(var + 1e-5);
    }
    __syncthreads();
    const double mean = sstat[0], inv = sstat[1];
    const float* g = (br == 0) ? gq : (br == 1) ? gk : gv;
    const float* b = (br == 0) ? bq : (br == 1) ? bk : bv;
    const double gc = (double)g[o], bc = (double)b[o];
    unsigned char* out = sbase + (size_t)br * PLANE + (size_t)o * N;
    #pragma unroll
    for (int j = 0; j < 16; ++j) {
        int l  = j * 256 + tid;
        int mm = l >> 10, nn = l & 1023;
        double t = gc * (v[j] - mean) * inv + bc;
        out[(size_t)mm * C * N + nn] = (t >= 1.0) ? (unsigned char)1 : (unsigned char)0;
    }
}

// ---------------------------------------------------------------------------
// Fused attention: kTv (popc over packed 0/1 bytes) + S = q . kTv, spike S>=2
// (== SCALE*S >= 0.5 with exact integers). grid = (4 n-chunks, 16 heads, 4 t).
// ---------------------------------------------------------------------------
__global__ __launch_bounds__(256) void attn_kernel(
    const unsigned char* __restrict__ qb, const unsigned char* __restrict__ kb,
    const unsigned char* __restrict__ vb, unsigned char* __restrict__ s2)
{
    const int nc = blockIdx.x;
    const int hh = blockIdx.y;
    const int t  = blockIdx.z;
    const int tid = threadIdx.x;

    __shared__ unsigned int kw[16][257];
    __shared__ unsigned int vw[16][257];
    __shared__ int kt[256];

    #pragma unroll
    for (int j = 0; j < 4; ++j) {
        int idx = j * 256 + tid;            // 0..1023 -> 16 rows x 64 uint4
        int r = idx >> 6, q4 = idx & 63;
        size_t goff = ((size_t)(t * C + hh * 16 + r)) * N + (size_t)q4 * 16;
        uint4 kk = *(const uint4*)(kb + goff);
        uint4 vv = *(const uint4*)(vb + goff);
        kw[r][q4 * 4 + 0] = kk.x; kw[r][q4 * 4 + 1] = kk.y;
        kw[r][q4 * 4 + 2] = kk.z; kw[r][q4 * 4 + 3] = kk.w;
        vw[r][q4 * 4 + 0] = vv.x; vw[r][q4 * 4 + 1] = vv.y;
        vw[r][q4 * 4 + 2] = vv.z; vw[r][q4 * 4 + 3] = vv.w;
    }
    __syncthreads();

    const int d = tid >> 4, dp = tid & 15;
    int sum = 0;
    #pragma unroll 8
    for (int wd = 0; wd < 256; ++wd)
        sum += __popc(kw[d][wd] & vw[dp][wd]);
    kt[tid] = sum;                          // kt[d*16+dp], exact integer
    __syncthreads();

    const int n = nc * 256 + tid;
    int sums[16];
    #pragma unroll
    for (int i = 0; i < 16; ++i) sums[i] = 0;
    #pragma unroll
    for (int d2 = 0; d2 < 16; ++d2) {
        int qv = (int)qb[((size_t)(t * C + hh * 16 + d2)) * N + n];
        #pragma unroll
        for (int dp2 = 0; dp2 < 16; ++dp2)
            sums[dp2] += qv * kt[d2 * 16 + dp2];
    }
    #pragma unroll
    for (int dp2 = 0; dp2 < 16; ++dp2)
        s2[((size_t)(t * C + hh * 16 + dp2)) * N + n] = (sums[dp2] >= 2) ? 1 : 0;
}

// ---------------------------------------------------------------------------
// Fused BN stats + spike for proj -> fp32 0/1 output. grid = (256)
// ---------------------------------------------------------------------------
__global__ __launch_bounds__(256) void bnspike_p(
    const double* __restrict__ hp,
    const float* __restrict__ gp, const float* __restrict__ bp,
    float* __restrict__ outp)
{
    const int o = blockIdx.x;
    const double* __restrict__ h = hp + (size_t)o * N;
    const int tid = threadIdx.x;

    double v[16];
    double s = 0.0, ss = 0.0;
    #pragma unroll
    for (int j = 0; j < 16; ++j) {
        int l  = j * 256 + tid;
        int mm = l >> 10, nn = l & 1023;
        v[j] = h[(size_t)mm * C * N + nn];
        s += v[j]; ss += v[j] * v[j];
    }
    #pragma unroll
    for (int off = 32; off > 0; off >>= 1) {
        s  += __shfl_down(s, off, 64);
        ss += __shfl_down(ss, off, 64);
    }
    __shared__ double rs[4], rss[4], sstat[2];
    const int lane = tid & 63, wv_ = tid >> 6;
    if (lane == 0) { rs[wv_] = s; rss[wv_] = ss; }
    __syncthreads();
    if (tid == 0) {
        double S  = rs[0] + rs[1] + rs[2] + rs[3];
        double SS = rss[0] + rss[1] + rss[2] + rss[3];
        double mean = S / 4096.0;
        double var  = SS / 4096.0 - mean * mean;
        sstat[0] = mean;
        sstat[1] = 1.0 / sqrt(var + 1e-5);
    }
    __syncthreads();
    const double mean = sstat[0], inv = sstat[1];
    const double gc = (double)gp[o], bc = (double)bp[o];
    float* out = outp + (size_t)o * N;
    #pragma unroll
    for (int j = 0; j < 16; ++j) {
        int l  = j * 256 + tid;
        int mm = l >> 10, nn = l & 1023;
        double t = gc * (v[j] - mean) * inv + bc;
        out[(size_t)mm * C * N + nn] = (t >= 1.0) ? 1.0f : 0.0f;
    }
}

// ---------------------------------------------------------------------------
extern "C" void kernel_launch(void* const* d_in, const int* in_sizes, int n_in,
                              void* d_out, int out_size, void* d_ws, size_t ws_size,
                              hipStream_t stream)
{
    const float* x  = (const float*)d_in[0];
    const float* y  = (const float*)d_in[1];
    const float* Wq = (const float*)d_in[2];
    const float* gq = (const float*)d_in[3];
    const float* bq = (const float*)d_in[4];
    const float* Wk = (const float*)d_in[5];
    const float* gk = (const float*)d_in[6];
    const float* bk = (const float*)d_in[7];
    const float* Wv = (const float*)d_in[8];
    const float* gv = (const float*)d_in[9];
    const float* bv = (const float*)d_in[10];
    const float* Wp = (const float*)d_in[11];
    const float* gp = (const float*)d_in[12];
    const float* bp = (const float*)d_in[13];
    float* out = (float*)d_out;

    // Workspace layout (28 MB total):
    //   [0, 24MB)  hq (3 branches fp64); hp (4 planes fp64) aliases [0,8MB)
    //   [24, 28MB) qb/kb/vb/s2b binary bytes
    char* ws = (char*)d_ws;
    double* hq = (double*)ws;
    double* hp = hq;                                      // alias: hq dead by then
    unsigned char* qb  = (unsigned char*)(ws + 3 * PLANE * sizeof(double));
    unsigned char* kb2 = qb + PLANE;
    unsigned char* vb2 = qb + 2 * PLANE;
    unsigned char* s2b = qb + 3 * PLANE;

    gemm_qkv<<<dim3(4, 16, 12), 256, 0, stream>>>(x, y, Wq, Wk, Wv, hq);
    bnspike_qkv<<<dim3(256, 3), 256, 0, stream>>>(hq, gq, bq, gk, bk, gv, bv, qb);
    attn_kernel<<<dim3(4, 16, 4), 256, 0, stream>>>(qb, kb2, vb2, s2b);
    gemm_p<<<dim3(4, 32, 4), 256, 0, stream>>>(s2b, Wp, hp);
    bnspike_p<<<dim3(256), 256, 0, stream>>>(hp, gp, bp, out);
}

// Round 6
// 154.938 us; speedup vs baseline: 1.2097x; 1.1835x over previous
//
#include <hip/hip_runtime.h>
#include <cstdint>
#include <cstddef>

static constexpr int C = 256;
static constexpr int N = 1024;
static constexpr int M = 4;                         // T*B
static constexpr size_t PLANE = (size_t)M * C * N;  // 1M elements per branch

typedef double d4 __attribute__((ext_vector_type(4)));

// Runtime-probe the C/D register->(row,col) mapping of v_mfma_f64_16x16x4.
// Assumes input layout A[m=lane&15][k=lane>>4], B[k=lane>>4][n=lane&15]
// (standard CDNA). Output mapping is read back from the hardware itself:
//   probe1: A[m][k]=delta(k==0)*m, B[k][n]=delta(k==0)   => D[m][n]=m
//   probe2: A[m][k]=delta(k==0),   B[k][n]=delta(k==0)*n => D[m][n]=n
__device__ inline void probe_d_layout(int lane, int rowv[4], int colv[4])
{
    const double am = (lane < 16) ? (double)lane : 0.0;
    const double a1 = (lane < 16) ? 1.0 : 0.0;
    const double bn = (lane < 16) ? (double)(lane & 15) : 0.0;
    d4 z = (d4){0.0, 0.0, 0.0, 0.0};
    d4 dr = __builtin_amdgcn_mfma_f64_16x16x4f64(am, a1, z, 0, 0, 0);
    d4 dc = __builtin_amdgcn_mfma_f64_16x16x4f64(a1, bn, z, 0, 0, 0);
    #pragma unroll
    for (int r = 0; r < 4; ++r) {
        rowv[r] = (int)dr[r];
        colv[r] = (int)dc[r];
    }
}

// ---------------------------------------------------------------------------
// fp64 MFMA GEMM: H[m][o][n] = sum_c W[o][c] * X[m][c][n]
// Block tile 64(o) x 64(n), 4 waves of 32x32 (2x2 mfma 16x16 accs),
// K-chunk 16, fp32 LDS staging (cvt at fragment read).
// grid = (16 n-tiles, 4 o-tiles, 12 planes[br*4+m])
// ---------------------------------------------------------------------------
__global__ __launch_bounds__(256) void gemm_qkv_mfma(
    const float* __restrict__ x, const float* __restrict__ y,
    const float* __restrict__ Wq, const float* __restrict__ Wk,
    const float* __restrict__ Wv, double* __restrict__ hbase)
{
    const int bz = blockIdx.z;           // 0..11
    const int br = bz >> 2;              // 0=q,1=k,2=v
    const int m  = bz & 3;
    const float* __restrict__ W = (br == 0) ? Wq : (br == 1) ? Wk : Wv;
    const float* __restrict__ X = ((br == 0) ? x : y) + (size_t)m * C * N;
    double* __restrict__ H = hbase + (size_t)br * PLANE + (size_t)m * C * N;

    const int n0 = blockIdx.x * 64;
    const int o0 = blockIdx.y * 64;
    const int tid  = threadIdx.x;
    const int lane = tid & 63;
    const int w    = tid >> 6;           // wave id 0..3
    const int ow   = (w & 1) * 32;       // wave o offset in block tile
    const int nw   = (w >> 1) * 32;      // wave n offset
    const int lm   = lane & 15;
    const int lk   = lane >> 4;

    int rowv[4], colv[4];
    probe_d_layout(lane, rowv, colv);

    __shared__ float As[64][20];         // [o][k]
    __shared__ float Bs[16][72];         // [k][n]

    d4 acc[2][2];
    #pragma unroll
    for (int i = 0; i < 2; ++i)
        #pragma unroll
        for (int j = 0; j < 2; ++j)
            acc[i][j] = (d4){0.0, 0.0, 0.0, 0.0};

    const int sa_o = tid >> 2;           // 0..63
    const int sa_q = (tid & 3) * 4;      // 0,4,8,12
    const int sb_c = tid >> 4;           // 0..15
    const int sb_q = (tid & 15) * 4;     // 0..60

    for (int c0 = 0; c0 < C; c0 += 16) {
        const float4 av = *(const float4*)(W + (size_t)(o0 + sa_o) * C + c0 + sa_q);
        const float4 bv = *(const float4*)(X + (size_t)(c0 + sb_c) * N + n0 + sb_q);
        *(float4*)(&As[sa_o][sa_q]) = av;
        *(float4*)(&Bs[sb_c][sb_q]) = bv;
        __syncthreads();
        #pragma unroll
        for (int ks = 0; ks < 4; ++ks) {
            const int kk = ks * 4 + lk;
            double a0 = (double)As[ow + lm][kk];
            double a1 = (double)As[ow + 16 + lm][kk];
            double b0 = (double)Bs[kk][nw + lm];
            double b1 = (double)Bs[kk][nw + 16 + lm];
            acc[0][0] = __builtin_amdgcn_mfma_f64_16x16x4f64(a0, b0, acc[0][0], 0, 0, 0);
            acc[0][1] = __builtin_amdgcn_mfma_f64_16x16x4f64(a0, b1, acc[0][1], 0, 0, 0);
            acc[1][0] = __builtin_amdgcn_mfma_f64_16x16x4f64(a1, b0, acc[1][0], 0, 0, 0);
            acc[1][1] = __builtin_amdgcn_mfma_f64_16x16x4f64(a1, b1, acc[1][1], 0, 0, 0);
        }
        __syncthreads();
    }

    #pragma unroll
    for (int ot = 0; ot < 2; ++ot)
        #pragma unroll
        for (int nt = 0; nt < 2; ++nt)
            #pragma unroll
            for (int r = 0; r < 4; ++r)
                H[(size_t)(o0 + ow + ot * 16 + rowv[r]) * N + (n0 + nw + nt * 16 + colv[r])] =
                    acc[ot][nt][r];
}

// Proj GEMM: same structure, binary uint8 X. grid = (16, 4, 4 planes)
__global__ __launch_bounds__(256) void gemm_p_mfma(
    const float* __restrict__ Wp, const unsigned char* __restrict__ s2,
    double* __restrict__ hp)
{
    const int m = blockIdx.z;
    const unsigned char* __restrict__ X = s2 + (size_t)m * C * N;
    double* __restrict__ H = hp + (size_t)m * C * N;

    const int n0 = blockIdx.x * 64;
    const int o0 = blockIdx.y * 64;
    const int tid  = threadIdx.x;
    const int lane = tid & 63;
    const int w    = tid >> 6;
    const int ow   = (w & 1) * 32;
    const int nw   = (w >> 1) * 32;
    const int lm   = lane & 15;
    const int lk   = lane >> 4;

    int rowv[4], colv[4];
    probe_d_layout(lane, rowv, colv);

    __shared__ float As[64][20];
    __shared__ float Bs[16][72];

    d4 acc[2][2];
    #pragma unroll
    for (int i = 0; i < 2; ++i)
        #pragma unroll
        for (int j = 0; j < 2; ++j)
            acc[i][j] = (d4){0.0, 0.0, 0.0, 0.0};

    const int sa_o = tid >> 2;
    const int sa_q = (tid & 3) * 4;
    const int sb_c = tid >> 4;
    const int sb_q = (tid & 15) * 4;

    for (int c0 = 0; c0 < C; c0 += 16) {
        const float4 av = *(const float4*)(Wp + (size_t)(o0 + sa_o) * C + c0 + sa_q);
        const unsigned int word = *(const unsigned int*)(X + (size_t)(c0 + sb_c) * N + n0 + sb_q);
        *(float4*)(&As[sa_o][sa_q]) = av;
        Bs[sb_c][sb_q + 0] = (float)(word & 0xFF);
        Bs[sb_c][sb_q + 1] = (float)((word >> 8) & 0xFF);
        Bs[sb_c][sb_q + 2] = (float)((word >> 16) & 0xFF);
        Bs[sb_c][sb_q + 3] = (float)((word >> 24) & 0xFF);
        __syncthreads();
        #pragma unroll
        for (int ks = 0; ks < 4; ++ks) {
            const int kk = ks * 4 + lk;
            double a0 = (double)As[ow + lm][kk];
            double a1 = (double)As[ow + 16 + lm][kk];
            double b0 = (double)Bs[kk][nw + lm];
            double b1 = (double)Bs[kk][nw + 16 + lm];
            acc[0][0] = __builtin_amdgcn_mfma_f64_16x16x4f64(a0, b0, acc[0][0], 0, 0, 0);
            acc[0][1] = __builtin_amdgcn_mfma_f64_16x16x4f64(a0, b1, acc[0][1], 0, 0, 0);
            acc[1][0] = __builtin_amdgcn_mfma_f64_16x16x4f64(a1, b0, acc[1][0], 0, 0, 0);
            acc[1][1] = __builtin_amdgcn_mfma_f64_16x16x4f64(a1, b1, acc[1][1], 0, 0, 0);
        }
        __syncthreads();
    }

    #pragma unroll
    for (int ot = 0; ot < 2; ++ot)
        #pragma unroll
        for (int nt = 0; nt < 2; ++nt)
            #pragma unroll
            for (int r = 0; r < 4; ++r)
                H[(size_t)(o0 + ow + ot * 16 + rowv[r]) * N + (n0 + nw + nt * 16 + colv[r])] =
                    acc[ot][nt][r];
}

// ---------------------------------------------------------------------------
// Fused BN stats + spike for q/k/v. Block = (channel o, branch br).
// ---------------------------------------------------------------------------
__global__ __launch_bounds__(256) void bnspike_qkv(
    const double* __restrict__ hbase,
    const float* __restrict__ gq, const float* __restrict__ bq,
    const float* __restrict__ gk, const float* __restrict__ bk,
    const float* __restrict__ gv, const float* __restrict__ bv,
    unsigned char* __restrict__ sbase)
{
    const int o  = blockIdx.x;
    const int br = blockIdx.y;
    const double* __restrict__ h = hbase + (size_t)br * PLANE + (size_t)o * N;
    const int tid = threadIdx.x;

    double v[16];
    double s = 0.0, ss = 0.0;
    #pragma unroll
    for (int j = 0; j < 16; ++j) {
        int l  = j * 256 + tid;             // 0..4095
        int mm = l >> 10, nn = l & 1023;
        v[j] = h[(size_t)mm * C * N + nn];
        s += v[j]; ss += v[j] * v[j];
    }
    #pragma unroll
    for (int off = 32; off > 0; off >>= 1) {
        s  += __shfl_down(s, off, 64);
        ss += __shfl_down(ss, off, 64);
    }
    __shared__ double rs[4], rss[4], sstat[2];
    const int lane = tid & 63, wv_ = tid >> 6;
    if (lane == 0) { rs[wv_] = s; rss[wv_] = ss; }
    __syncthreads();
    if (tid == 0) {
        double S  = rs[0] + rs[1] + rs[2] + rs[3];
        double SS = rss[0] + rss[1] + rss[2] + rss[3];
        double mean = S / 4096.0;
        double var  = SS / 4096.0 - mean * mean;
        sstat[0] = mean;
        sstat[1] = 1.0 / sqrt(var + 1e-5);
    }
    __syncthreads();
    const double mean = sstat[0], inv = sstat[1];
    const float* g = (br == 0) ? gq : (br == 1) ? gk : gv;
    const float* b = (br == 0) ? bq : (br == 1) ? bk : bv;
    const double gc = (double)g[o], bc = (double)b[o];
    unsigned char* out = sbase + (size_t)br * PLANE + (size_t)o * N;
    #pragma unroll
    for (int j = 0; j < 16; ++j) {
        int l  = j * 256 + tid;
        int mm = l >> 10, nn = l & 1023;
        double t = gc * (v[j] - mean) * inv + bc;
        out[(size_t)mm * C * N + nn] = (t >= 1.0) ? (unsigned char)1 : (unsigned char)0;
    }
}

// ---------------------------------------------------------------------------
// Fused attention: kTv (popc over packed 0/1 bytes) + S = q . kTv, spike S>=2
// (== SCALE*S >= 0.5 with exact integers). grid = (4 n-chunks, 16 heads, 4 t).
// ---------------------------------------------------------------------------
__global__ __launch_bounds__(256) void attn_kernel(
    const unsigned char* __restrict__ qb, const unsigned char* __restrict__ kb,
    const unsigned char* __restrict__ vb, unsigned char* __restrict__ s2)
{
    const int nc = blockIdx.x;
    const int hh = blockIdx.y;
    const int t  = blockIdx.z;
    const int tid = threadIdx.x;

    __shared__ unsigned int kw[16][257];
    __shared__ unsigned int vw[16][257];
    __shared__ int kt[256];

    #pragma unroll
    for (int j = 0; j < 4; ++j) {
        int idx = j * 256 + tid;            // 0..1023 -> 16 rows x 64 uint4
        int r = idx >> 6, q4 = idx & 63;
        size_t goff = ((size_t)(t * C + hh * 16 + r)) * N + (size_t)q4 * 16;
        uint4 kk = *(const uint4*)(kb + goff);
        uint4 vv = *(const uint4*)(vb + goff);
        kw[r][q4 * 4 + 0] = kk.x; kw[r][q4 * 4 + 1] = kk.y;
        kw[r][q4 * 4 + 2] = kk.z; kw[r][q4 * 4 + 3] = kk.w;
        vw[r][q4 * 4 + 0] = vv.x; vw[r][q4 * 4 + 1] = vv.y;
        vw[r][q4 * 4 + 2] = vv.z; vw[r][q4 * 4 + 3] = vv.w;
    }
    __syncthreads();

    const int d = tid >> 4, dp = tid & 15;
    int sum = 0;
    #pragma unroll 8
    for (int wd = 0; wd < 256; ++wd)
        sum += __popc(kw[d][wd] & vw[dp][wd]);
    kt[tid] = sum;                          // kt[d*16+dp], exact integer
    __syncthreads();

    const int n = nc * 256 + tid;
    int sums[16];
    #pragma unroll
    for (int i = 0; i < 16; ++i) sums[i] = 0;
    #pragma unroll
    for (int d2 = 0; d2 < 16; ++d2) {
        int qv = (int)qb[((size_t)(t * C + hh * 16 + d2)) * N + n];
        #pragma unroll
        for (int dp2 = 0; dp2 < 16; ++dp2)
            sums[dp2] += qv * kt[d2 * 16 + dp2];
    }
    #pragma unroll
    for (int dp2 = 0; dp2 < 16; ++dp2)
        s2[((size_t)(t * C + hh * 16 + dp2)) * N + n] = (sums[dp2] >= 2) ? 1 : 0;
}

// ---------------------------------------------------------------------------
// Fused BN stats + spike for proj -> fp32 0/1 output. grid = (256)
// ---------------------------------------------------------------------------
__global__ __launch_bounds__(256) void bnspike_p(
    const double* __restrict__ hp,
    const float* __restrict__ gp, const float* __restrict__ bp,
    float* __restrict__ outp)
{
    const int o = blockIdx.x;
    const double* __restrict__ h = hp + (size_t)o * N;
    const int tid = threadIdx.x;

    double v[16];
    double s = 0.0, ss = 0.0;
    #pragma unroll
    for (int j = 0; j < 16; ++j) {
        int l  = j * 256 + tid;
        int mm = l >> 10, nn = l & 1023;
        v[j] = h[(size_t)mm * C * N + nn];
        s += v[j]; ss += v[j] * v[j];
    }
    #pragma unroll
    for (int off = 32; off > 0; off >>= 1) {
        s  += __shfl_down(s, off, 64);
        ss += __shfl_down(ss, off, 64);
    }
    __shared__ double rs[4], rss[4], sstat[2];
    const int lane = tid & 63, wv_ = tid >> 6;
    if (lane == 0) { rs[wv_] = s; rss[wv_] = ss; }
    __syncthreads();
    if (tid == 0) {
        double S  = rs[0] + rs[1] + rs[2] + rs[3];
        double SS = rss[0] + rss[1] + rss[2] + rss[3];
        double mean = S / 4096.0;
        double var  = SS / 4096.0 - mean * mean;
        sstat[0] = mean;
        sstat[1] = 1.0 / sqrt(var + 1e-5);
    }
    __syncthreads();
    const double mean = sstat[0], inv = sstat[1];
    const double gc = (double)gp[o], bc = (double)bp[o];
    float* out = outp + (size_t)o * N;
    #pragma unroll
    for (int j = 0; j < 16; ++j) {
        int l  = j * 256 + tid;
        int mm = l >> 10, nn = l & 1023;
        double t = gc * (v[j] - mean) * inv + bc;
        out[(size_t)mm * C * N + nn] = (t >= 1.0) ? 1.0f : 0.0f;
    }
}

// ---------------------------------------------------------------------------
extern "C" void kernel_launch(void* const* d_in, const int* in_sizes, int n_in,
                              void* d_out, int out_size, void* d_ws, size_t ws_size,
                              hipStream_t stream)
{
    const float* x  = (const float*)d_in[0];
    const float* y  = (const float*)d_in[1];
    const float* Wq = (const float*)d_in[2];
    const float* gq = (const float*)d_in[3];
    const float* bq = (const float*)d_in[4];
    const float* Wk = (const float*)d_in[5];
    const float* gk = (const float*)d_in[6];
    const float* bk = (const float*)d_in[7];
    const float* Wv = (const float*)d_in[8];
    const float* gv = (const float*)d_in[9];
    const float* bv = (const float*)d_in[10];
    const float* Wp = (const float*)d_in[11];
    const float* gp = (const float*)d_in[12];
    const float* bp = (const float*)d_in[13];
    float* out = (float*)d_out;

    // Workspace layout (28 MB):
    //   [0, 24MB)  hq (3 branches fp64); hp (4 planes fp64) aliases [0,8MB)
    //   [24, 28MB) qb/kb/vb/s2b binary bytes
    char* ws = (char*)d_ws;
    double* hq = (double*)ws;
    double* hp = hq;                                      // alias: hq dead by then
    unsigned char* qb  = (unsigned char*)(ws + 3 * PLANE * sizeof(double));
    unsigned char* kb2 = qb + PLANE;
    unsigned char* vb2 = qb + 2 * PLANE;
    unsigned char* s2b = qb + 3 * PLANE;

    gemm_qkv_mfma<<<dim3(16, 4, 12), 256, 0, stream>>>(x, y, Wq, Wk, Wv, hq);
    bnspike_qkv<<<dim3(256, 3), 256, 0, stream>>>(hq, gq, bq, gk, bk, gv, bv, qb);
    attn_kernel<<<dim3(4, 16, 4), 256, 0, stream>>>(qb, kb2, vb2, s2b);
    gemm_p_mfma<<<dim3(16, 4, 4), 256, 0, stream>>>(Wp, s2b, hp);
    bnspike_p<<<dim3(256), 256, 0, stream>>>(hp, gp, bp, out);
}

// Round 7
// 149.532 us; speedup vs baseline: 1.2535x; 1.0362x over previous
//
#include <hip/hip_runtime.h>
#include <cstdint>
#include <cstddef>

static constexpr int C = 256;
static constexpr int N = 1024;
static constexpr int M = 4;                         // T*B
static constexpr size_t PLANE = (size_t)M * C * N;  // 1M elements per branch

typedef double d4 __attribute__((ext_vector_type(4)));

// Runtime-probe the C/D register->(row,col) mapping of v_mfma_f64_16x16x4.
// Assumes input layout A[m=lane&15][k=lane>>4], B[k=lane>>4][n=lane&15]
// (standard CDNA; verified by R6 passing with absmax 0).
__device__ inline void probe_d_layout(int lane, int rowv[4], int colv[4])
{
    const double am = (lane < 16) ? (double)lane : 0.0;
    const double a1 = (lane < 16) ? 1.0 : 0.0;
    const double bn = (lane < 16) ? (double)(lane & 15) : 0.0;
    d4 z = (d4){0.0, 0.0, 0.0, 0.0};
    d4 dr = __builtin_amdgcn_mfma_f64_16x16x4f64(am, a1, z, 0, 0, 0);
    d4 dc = __builtin_amdgcn_mfma_f64_16x16x4f64(a1, bn, z, 0, 0, 0);
    #pragma unroll
    for (int r = 0; r < 4; ++r) {
        rowv[r] = (int)dr[r];
        colv[r] = (int)dc[r];
    }
}

// LDS strides (floats): chosen for float4-aligned writes and <=2-way bank
// aliasing on the b32 fragment reads (2-way is free on gfx950).
static constexpr int ASTR = 36;   // A[o][k], k-chunk 32
static constexpr int BSTR = 72;   // B[k][n], n-tile 64

// ---------------------------------------------------------------------------
// fp64 MFMA GEMM: H[m][o][n] = sum_c W[o][c] * X[m][c][n]
// Block tile 64(o) x 64(n), 4 waves of 32x32 (2x2 mfma 16x16 accs).
// K-chunk 32, double-buffered fp32 LDS staging, ONE barrier per chunk.
// grid = (16 n-tiles, 4 o-tiles, 12 planes[br*4+m])
// ---------------------------------------------------------------------------
__global__ __launch_bounds__(256) void gemm_qkv_mfma(
    const float* __restrict__ x, const float* __restrict__ y,
    const float* __restrict__ Wq, const float* __restrict__ Wk,
    const float* __restrict__ Wv, double* __restrict__ hbase)
{
    const int bz = blockIdx.z;           // 0..11
    const int br = bz >> 2;              // 0=q,1=k,2=v
    const int m  = bz & 3;
    const float* __restrict__ W = (br == 0) ? Wq : (br == 1) ? Wk : Wv;
    const float* __restrict__ X = ((br == 0) ? x : y) + (size_t)m * C * N;
    double* __restrict__ H = hbase + (size_t)br * PLANE + (size_t)m * C * N;

    const int n0 = blockIdx.x * 64;
    const int o0 = blockIdx.y * 64;
    const int tid  = threadIdx.x;
    const int lane = tid & 63;
    const int w    = tid >> 6;           // wave id 0..3
    const int ow   = (w & 1) * 32;       // wave o offset in block tile
    const int nw   = (w >> 1) * 32;      // wave n offset
    const int lm   = lane & 15;
    const int lk   = lane >> 4;

    int rowv[4], colv[4];
    probe_d_layout(lane, rowv, colv);

    __shared__ __align__(16) float As[2][64 * ASTR];   // ~18.4 KB
    __shared__ __align__(16) float Bs[2][32 * BSTR];   // ~18.4 KB

    d4 acc[2][2];
    #pragma unroll
    for (int i = 0; i < 2; ++i)
        #pragma unroll
        for (int j = 0; j < 2; ++j)
            acc[i][j] = (d4){0.0, 0.0, 0.0, 0.0};

    // staging: A tile 64 o x 32 k (2048 floats), B tile 32 k x 64 n (2048)
    const int rA = tid >> 2;             // 0..63
    const int cA = (tid & 3) * 8;        // 0,8,16,24
    const int rB = tid >> 3;             // 0..31
    const int cB = (tid & 7) * 8;        // 0..56

    float4 a0r, a1r, b0r, b1r;
    // prologue: chunk 0
    a0r = *(const float4*)(W + (size_t)(o0 + rA) * C + 0 + cA);
    a1r = *(const float4*)(W + (size_t)(o0 + rA) * C + 0 + cA + 4);
    b0r = *(const float4*)(X + (size_t)(0 + rB) * N + n0 + cB);
    b1r = *(const float4*)(X + (size_t)(0 + rB) * N + n0 + cB + 4);

    int buf = 0;
    for (int ch = 0; ch < 8; ++ch) {
        *(float4*)(&As[buf][rA * ASTR + cA])     = a0r;
        *(float4*)(&As[buf][rA * ASTR + cA + 4]) = a1r;
        *(float4*)(&Bs[buf][rB * BSTR + cB])     = b0r;
        *(float4*)(&Bs[buf][rB * BSTR + cB + 4]) = b1r;
        __syncthreads();
        if (ch < 7) {
            const int c0 = (ch + 1) * 32;
            a0r = *(const float4*)(W + (size_t)(o0 + rA) * C + c0 + cA);
            a1r = *(const float4*)(W + (size_t)(o0 + rA) * C + c0 + cA + 4);
            b0r = *(const float4*)(X + (size_t)(c0 + rB) * N + n0 + cB);
            b1r = *(const float4*)(X + (size_t)(c0 + rB) * N + n0 + cB + 4);
        }
        const float* __restrict__ Ab = As[buf];
        const float* __restrict__ Bb = Bs[buf];
        #pragma unroll
        for (int ks = 0; ks < 8; ++ks) {
            const int kk = ks * 4 + lk;
            double a0 = (double)Ab[(ow + lm) * ASTR + kk];
            double a1 = (double)Ab[(ow + 16 + lm) * ASTR + kk];
            double b0 = (double)Bb[kk * BSTR + nw + lm];
            double b1 = (double)Bb[kk * BSTR + nw + 16 + lm];
            acc[0][0] = __builtin_amdgcn_mfma_f64_16x16x4f64(a0, b0, acc[0][0], 0, 0, 0);
            acc[0][1] = __builtin_amdgcn_mfma_f64_16x16x4f64(a0, b1, acc[0][1], 0, 0, 0);
            acc[1][0] = __builtin_amdgcn_mfma_f64_16x16x4f64(a1, b0, acc[1][0], 0, 0, 0);
            acc[1][1] = __builtin_amdgcn_mfma_f64_16x16x4f64(a1, b1, acc[1][1], 0, 0, 0);
        }
        buf ^= 1;
    }

    #pragma unroll
    for (int ot = 0; ot < 2; ++ot)
        #pragma unroll
        for (int nt = 0; nt < 2; ++nt)
            #pragma unroll
            for (int r = 0; r < 4; ++r)
                H[(size_t)(o0 + ow + ot * 16 + rowv[r]) * N + (n0 + nw + nt * 16 + colv[r])] =
                    acc[ot][nt][r];
}

// Proj GEMM: same structure, binary uint8 X. grid = (16, 4, 4 planes)
__global__ __launch_bounds__(256) void gemm_p_mfma(
    const float* __restrict__ Wp, const unsigned char* __restrict__ s2,
    double* __restrict__ hp)
{
    const int m = blockIdx.z;
    const unsigned char* __restrict__ X = s2 + (size_t)m * C * N;
    double* __restrict__ H = hp + (size_t)m * C * N;

    const int n0 = blockIdx.x * 64;
    const int o0 = blockIdx.y * 64;
    const int tid  = threadIdx.x;
    const int lane = tid & 63;
    const int w    = tid >> 6;
    const int ow   = (w & 1) * 32;
    const int nw   = (w >> 1) * 32;
    const int lm   = lane & 15;
    const int lk   = lane >> 4;

    int rowv[4], colv[4];
    probe_d_layout(lane, rowv, colv);

    __shared__ __align__(16) float As[2][64 * ASTR];
    __shared__ __align__(16) float Bs[2][32 * BSTR];

    d4 acc[2][2];
    #pragma unroll
    for (int i = 0; i < 2; ++i)
        #pragma unroll
        for (int j = 0; j < 2; ++j)
            acc[i][j] = (d4){0.0, 0.0, 0.0, 0.0};

    const int rA = tid >> 2;
    const int cA = (tid & 3) * 8;
    const int rB = tid >> 3;
    const int cB = (tid & 7) * 8;

    float4 a0r, a1r;
    uint2 bw;
    a0r = *(const float4*)(Wp + (size_t)(o0 + rA) * C + 0 + cA);
    a1r = *(const float4*)(Wp + (size_t)(o0 + rA) * C + 0 + cA + 4);
    bw  = *(const uint2*)(X + (size_t)(0 + rB) * N + n0 + cB);

    int buf = 0;
    for (int ch = 0; ch < 8; ++ch) {
        *(float4*)(&As[buf][rA * ASTR + cA])     = a0r;
        *(float4*)(&As[buf][rA * ASTR + cA + 4]) = a1r;
        float* bs = &Bs[buf][rB * BSTR + cB];
        bs[0] = (float)(bw.x & 0xFF);
        bs[1] = (float)((bw.x >> 8) & 0xFF);
        bs[2] = (float)((bw.x >> 16) & 0xFF);
        bs[3] = (float)((bw.x >> 24) & 0xFF);
        bs[4] = (float)(bw.y & 0xFF);
        bs[5] = (float)((bw.y >> 8) & 0xFF);
        bs[6] = (float)((bw.y >> 16) & 0xFF);
        bs[7] = (float)((bw.y >> 24) & 0xFF);
        __syncthreads();
        if (ch < 7) {
            const int c0 = (ch + 1) * 32;
            a0r = *(const float4*)(Wp + (size_t)(o0 + rA) * C + c0 + cA);
            a1r = *(const float4*)(Wp + (size_t)(o0 + rA) * C + c0 + cA + 4);
            bw  = *(const uint2*)(X + (size_t)(c0 + rB) * N + n0 + cB);
        }
        const float* __restrict__ Ab = As[buf];
        const float* __restrict__ Bb = Bs[buf];
        #pragma unroll
        for (int ks = 0; ks < 8; ++ks) {
            const int kk = ks * 4 + lk;
            double a0 = (double)Ab[(ow + lm) * ASTR + kk];
            double a1 = (double)Ab[(ow + 16 + lm) * ASTR + kk];
            double b0 = (double)Bb[kk * BSTR + nw + lm];
            double b1 = (double)Bb[kk * BSTR + nw + 16 + lm];
            acc[0][0] = __builtin_amdgcn_mfma_f64_16x16x4f64(a0, b0, acc[0][0], 0, 0, 0);
            acc[0][1] = __builtin_amdgcn_mfma_f64_16x16x4f64(a0, b1, acc[0][1], 0, 0, 0);
            acc[1][0] = __builtin_amdgcn_mfma_f64_16x16x4f64(a1, b0, acc[1][0], 0, 0, 0);
            acc[1][1] = __builtin_amdgcn_mfma_f64_16x16x4f64(a1, b1, acc[1][1], 0, 0, 0);
        }
        buf ^= 1;
    }

    #pragma unroll
    for (int ot = 0; ot < 2; ++ot)
        #pragma unroll
        for (int nt = 0; nt < 2; ++nt)
            #pragma unroll
            for (int r = 0; r < 4; ++r)
                H[(size_t)(o0 + ow + ot * 16 + rowv[r]) * N + (n0 + nw + nt * 16 + colv[r])] =
                    acc[ot][nt][r];
}

// ---------------------------------------------------------------------------
// Fused BN stats + spike for q/k/v. Block = (channel o, branch br).
// ---------------------------------------------------------------------------
__global__ __launch_bounds__(256) void bnspike_qkv(
    const double* __restrict__ hbase,
    const float* __restrict__ gq, const float* __restrict__ bq,
    const float* __restrict__ gk, const float* __restrict__ bk,
    const float* __restrict__ gv, const float* __restrict__ bv,
    unsigned char* __restrict__ sbase)
{
    const int o  = blockIdx.x;
    const int br = blockIdx.y;
    const double* __restrict__ h = hbase + (size_t)br * PLANE + (size_t)o * N;
    const int tid = threadIdx.x;

    double v[16];
    double s = 0.0, ss = 0.0;
    #pragma unroll
    for (int j = 0; j < 16; ++j) {
        int l  = j * 256 + tid;             // 0..4095
        int mm = l >> 10, nn = l & 1023;
        v[j] = h[(size_t)mm * C * N + nn];
        s += v[j]; ss += v[j] * v[j];
    }
    #pragma unroll
    for (int off = 32; off > 0; off >>= 1) {
        s  += __shfl_down(s, off, 64);
        ss += __shfl_down(ss, off, 64);
    }
    __shared__ double rs[4], rss[4], sstat[2];
    const int lane = tid & 63, wv_ = tid >> 6;
    if (lane == 0) { rs[wv_] = s; rss[wv_] = ss; }
    __syncthreads();
    if (tid == 0) {
        double S  = rs[0] + rs[1] + rs[2] + rs[3];
        double SS = rss[0] + rss[1] + rss[2] + rss[3];
        double mean = S / 4096.0;
        double var  = SS / 4096.0 - mean * mean;
        sstat[0] = mean;
        sstat[1] = 1.0 / sqrt(var + 1e-5);
    }
    __syncthreads();
    const double mean = sstat[0], inv = sstat[1];
    const float* g = (br == 0) ? gq : (br == 1) ? gk : gv;
    const float* b = (br == 0) ? bq : (br == 1) ? bk : bv;
    const double gc = (double)g[o], bc = (double)b[o];
    unsigned char* out = sbase + (size_t)br * PLANE + (size_t)o * N;
    #pragma unroll
    for (int j = 0; j < 16; ++j) {
        int l  = j * 256 + tid;
        int mm = l >> 10, nn = l & 1023;
        double t = gc * (v[j] - mean) * inv + bc;
        out[(size_t)mm * C * N + nn] = (t >= 1.0) ? (unsigned char)1 : (unsigned char)0;
    }
}

// ---------------------------------------------------------------------------
// Fused attention: kTv (popc over packed 0/1 bytes) + S = q . kTv, spike S>=2
// (== SCALE*S >= 0.5 with exact integers). grid = (4 n-chunks, 16 heads, 4 t).
// ---------------------------------------------------------------------------
__global__ __launch_bounds__(256) void attn_kernel(
    const unsigned char* __restrict__ qb, const unsigned char* __restrict__ kb,
    const unsigned char* __restrict__ vb, unsigned char* __restrict__ s2)
{
    const int nc = blockIdx.x;
    const int hh = blockIdx.y;
    const int t  = blockIdx.z;
    const int tid = threadIdx.x;

    __shared__ unsigned int kw[16][257];
    __shared__ unsigned int vw[16][257];
    __shared__ int kt[256];

    #pragma unroll
    for (int j = 0; j < 4; ++j) {
        int idx = j * 256 + tid;            // 0..1023 -> 16 rows x 64 uint4
        int r = idx >> 6, q4 = idx & 63;
        size_t goff = ((size_t)(t * C + hh * 16 + r)) * N + (size_t)q4 * 16;
        uint4 kk = *(const uint4*)(kb + goff);
        uint4 vv = *(const uint4*)(vb + goff);
        kw[r][q4 * 4 + 0] = kk.x; kw[r][q4 * 4 + 1] = kk.y;
        kw[r][q4 * 4 + 2] = kk.z; kw[r][q4 * 4 + 3] = kk.w;
        vw[r][q4 * 4 + 0] = vv.x; vw[r][q4 * 4 + 1] = vv.y;
        vw[r][q4 * 4 + 2] = vv.z; vw[r][q4 * 4 + 3] = vv.w;
    }
    __syncthreads();

    const int d = tid >> 4, dp = tid & 15;
    int sum = 0;
    #pragma unroll 8
    for (int wd = 0; wd < 256; ++wd)
        sum += __popc(kw[d][wd] & vw[dp][wd]);
    kt[tid] = sum;                          // kt[d*16+dp], exact integer
    __syncthreads();

    const int n = nc * 256 + tid;
    int sums[16];
    #pragma unroll
    for (int i = 0; i < 16; ++i) sums[i] = 0;
    #pragma unroll
    for (int d2 = 0; d2 < 16; ++d2) {
        int qv = (int)qb[((size_t)(t * C + hh * 16 + d2)) * N + n];
        #pragma unroll
        for (int dp2 = 0; dp2 < 16; ++dp2)
            sums[dp2] += qv * kt[d2 * 16 + dp2];
    }
    #pragma unroll
    for (int dp2 = 0; dp2 < 16; ++dp2)
        s2[((size_t)(t * C + hh * 16 + dp2)) * N + n] = (sums[dp2] >= 2) ? 1 : 0;
}

// ---------------------------------------------------------------------------
// Fused BN stats + spike for proj -> fp32 0/1 output. grid = (256)
// ---------------------------------------------------------------------------
__global__ __launch_bounds__(256) void bnspike_p(
    const double* __restrict__ hp,
    const float* __restrict__ gp, const float* __restrict__ bp,
    float* __restrict__ outp)
{
    const int o = blockIdx.x;
    const double* __restrict__ h = hp + (size_t)o * N;
    const int tid = threadIdx.x;

    double v[16];
    double s = 0.0, ss = 0.0;
    #pragma unroll
    for (int j = 0; j < 16; ++j) {
        int l  = j * 256 + tid;
        int mm = l >> 10, nn = l & 1023;
        v[j] = h[(size_t)mm * C * N + nn];
        s += v[j]; ss += v[j] * v[j];
    }
    #pragma unroll
    for (int off = 32; off > 0; off >>= 1) {
        s  += __shfl_down(s, off, 64);
        ss += __shfl_down(ss, off, 64);
    }
    __shared__ double rs[4], rss[4], sstat[2];
    const int lane = tid & 63, wv_ = tid >> 6;
    if (lane == 0) { rs[wv_] = s; rss[wv_] = ss; }
    __syncthreads();
    if (tid == 0) {
        double S  = rs[0] + rs[1] + rs[2] + rs[3];
        double SS = rss[0] + rss[1] + rss[2] + rss[3];
        double mean = S / 4096.0;
        double var  = SS / 4096.0 - mean * mean;
        sstat[0] = mean;
        sstat[1] = 1.0 / sqrt(var + 1e-5);
    }
    __syncthreads();
    const double mean = sstat[0], inv = sstat[1];
    const double gc = (double)gp[o], bc = (double)bp[o];
    float* out = outp + (size_t)o * N;
    #pragma unroll
    for (int j = 0; j < 16; ++j) {
        int l  = j * 256 + tid;
        int mm = l >> 10, nn = l & 1023;
        double t = gc * (v[j] - mean) * inv + bc;
        out[(size_t)mm * C * N + nn] = (t >= 1.0) ? 1.0f : 0.0f;
    }
}

// ---------------------------------------------------------------------------
extern "C" void kernel_launch(void* const* d_in, const int* in_sizes, int n_in,
                              void* d_out, int out_size, void* d_ws, size_t ws_size,
                              hipStream_t stream)
{
    const float* x  = (const float*)d_in[0];
    const float* y  = (const float*)d_in[1];
    const float* Wq = (const float*)d_in[2];
    const float* gq = (const float*)d_in[3];
    const float* bq = (const float*)d_in[4];
    const float* Wk = (const float*)d_in[5];
    const float* gk = (const float*)d_in[6];
    const float* bk = (const float*)d_in[7];
    const float* Wv = (const float*)d_in[8];
    const float* gv = (const float*)d_in[9];
    const float* bv = (const float*)d_in[10];
    const float* Wp = (const float*)d_in[11];
    const float* gp = (const float*)d_in[12];
    const float* bp = (const float*)d_in[13];
    float* out = (float*)d_out;

    // Workspace layout (28 MB):
    //   [0, 24MB)  hq (3 branches fp64); hp (4 planes fp64) aliases [0,8MB)
    //   [24, 28MB) qb/kb/vb/s2b binary bytes
    char* ws = (char*)d_ws;
    double* hq = (double*)ws;
    double* hp = hq;                                      // alias: hq dead by then
    unsigned char* qb  = (unsigned char*)(ws + 3 * PLANE * sizeof(double));
    unsigned char* kb2 = qb + PLANE;
    unsigned char* vb2 = qb + 2 * PLANE;
    unsigned char* s2b = qb + 3 * PLANE;

    gemm_qkv_mfma<<<dim3(16, 4, 12), 256, 0, stream>>>(x, y, Wq, Wk, Wv, hq);
    bnspike_qkv<<<dim3(256, 3), 256, 0, stream>>>(hq, gq, bq, gk, bk, gv, bv, qb);
    attn_kernel<<<dim3(4, 16, 4), 256, 0, stream>>>(qb, kb2, vb2, s2b);
    gemm_p_mfma<<<dim3(16, 4, 4), 256, 0, stream>>>(Wp, s2b, hp);
    bnspike_p<<<dim3(256), 256, 0, stream>>>(hp, gp, bp, out);
}

// Round 8
// 148.440 us; speedup vs baseline: 1.2627x; 1.0074x over previous
//
#include <hip/hip_runtime.h>
#include <cstdint>
#include <cstddef>

static constexpr int C = 256;
static constexpr int N = 1024;
static constexpr int M = 4;                         // T*B
static constexpr size_t PLANE = (size_t)M * C * N;  // 1M elements per branch

typedef double d4 __attribute__((ext_vector_type(4)));

// Runtime-probe the C/D register->(row,col) mapping of v_mfma_f64_16x16x4.
// Input layout A[m=lane&15][k=lane>>4], B[k=lane>>4][n=lane&15] (verified:
// R6/R7 pass with absmax 0).
__device__ inline void probe_d_layout(int lane, int rowv[4], int colv[4])
{
    const double am = (lane < 16) ? (double)lane : 0.0;
    const double a1 = (lane < 16) ? 1.0 : 0.0;
    const double bn = (lane < 16) ? (double)(lane & 15) : 0.0;
    d4 z = (d4){0.0, 0.0, 0.0, 0.0};
    d4 dr = __builtin_amdgcn_mfma_f64_16x16x4f64(am, a1, z, 0, 0, 0);
    d4 dc = __builtin_amdgcn_mfma_f64_16x16x4f64(a1, bn, z, 0, 0, 0);
    #pragma unroll
    for (int r = 0; r < 4; ++r) {
        rowv[r] = (int)dr[r];
        colv[r] = (int)dc[r];
    }
}

static constexpr int ASTR = 36;   // A[o][k] lds stride (floats): <=2-way banks
static constexpr int BSTR = 72;   // B[k][n] lds stride

// ---------------------------------------------------------------------------
// fp64 MFMA GEMM: H[m][o][n] = sum_c W[o][c] * X[m][c][n]
// Block tile 64(o) x 64(n), 4 waves of 32x32 (2x2 16x16 accs).
// K-chunk 32, double-buffered fp32 LDS staging, ONE barrier per chunk.
// grid = (16 n-tiles, 4 o-tiles, 12 planes[br*4+m])
// ---------------------------------------------------------------------------
__global__ __launch_bounds__(256) void gemm_qkv_mfma(
    const float* __restrict__ x, const float* __restrict__ y,
    const float* __restrict__ Wq, const float* __restrict__ Wk,
    const float* __restrict__ Wv, double* __restrict__ hbase)
{
    const int bz = blockIdx.z;           // 0..11
    const int br = bz >> 2;              // 0=q,1=k,2=v
    const int m  = bz & 3;
    const float* __restrict__ W = (br == 0) ? Wq : (br == 1) ? Wk : Wv;
    const float* __restrict__ X = ((br == 0) ? x : y) + (size_t)m * C * N;
    double* __restrict__ H = hbase + (size_t)br * PLANE + (size_t)m * C * N;

    const int n0 = blockIdx.x * 64;
    const int o0 = blockIdx.y * 64;
    const int tid  = threadIdx.x;
    const int lane = tid & 63;
    const int w    = tid >> 6;           // wave id 0..3
    const int ow   = (w & 1) * 32;
    const int nw   = (w >> 1) * 32;
    const int lm   = lane & 15;
    const int lk   = lane >> 4;

    int rowv[4], colv[4];
    probe_d_layout(lane, rowv, colv);

    __shared__ __align__(16) float As[2][64 * ASTR];
    __shared__ __align__(16) float Bs[2][32 * BSTR];

    d4 acc[2][2];
    #pragma unroll
    for (int i = 0; i < 2; ++i)
        #pragma unroll
        for (int j = 0; j < 2; ++j)
            acc[i][j] = (d4){0.0, 0.0, 0.0, 0.0};

    const int rA = tid >> 2;             // 0..63
    const int cA = (tid & 3) * 8;        // 0,8,16,24
    const int rB = tid >> 3;             // 0..31
    const int cB = (tid & 7) * 8;        // 0..56

    float4 a0r, a1r, b0r, b1r;
    a0r = *(const float4*)(W + (size_t)(o0 + rA) * C + 0 + cA);
    a1r = *(const float4*)(W + (size_t)(o0 + rA) * C + 0 + cA + 4);
    b0r = *(const float4*)(X + (size_t)(0 + rB) * N + n0 + cB);
    b1r = *(const float4*)(X + (size_t)(0 + rB) * N + n0 + cB + 4);

    int buf = 0;
    for (int ch = 0; ch < 8; ++ch) {
        *(float4*)(&As[buf][rA * ASTR + cA])     = a0r;
        *(float4*)(&As[buf][rA * ASTR + cA + 4]) = a1r;
        *(float4*)(&Bs[buf][rB * BSTR + cB])     = b0r;
        *(float4*)(&Bs[buf][rB * BSTR + cB + 4]) = b1r;
        __syncthreads();
        if (ch < 7) {
            const int c0 = (ch + 1) * 32;
            a0r = *(const float4*)(W + (size_t)(o0 + rA) * C + c0 + cA);
            a1r = *(const float4*)(W + (size_t)(o0 + rA) * C + c0 + cA + 4);
            b0r = *(const float4*)(X + (size_t)(c0 + rB) * N + n0 + cB);
            b1r = *(const float4*)(X + (size_t)(c0 + rB) * N + n0 + cB + 4);
        }
        const float* __restrict__ Ab = As[buf];
        const float* __restrict__ Bb = Bs[buf];
        #pragma unroll
        for (int ks = 0; ks < 8; ++ks) {
            const int kk = ks * 4 + lk;
            double a0 = (double)Ab[(ow + lm) * ASTR + kk];
            double a1 = (double)Ab[(ow + 16 + lm) * ASTR + kk];
            double b0 = (double)Bb[kk * BSTR + nw + lm];
            double b1 = (double)Bb[kk * BSTR + nw + 16 + lm];
            acc[0][0] = __builtin_amdgcn_mfma_f64_16x16x4f64(a0, b0, acc[0][0], 0, 0, 0);
            acc[0][1] = __builtin_amdgcn_mfma_f64_16x16x4f64(a0, b1, acc[0][1], 0, 0, 0);
            acc[1][0] = __builtin_amdgcn_mfma_f64_16x16x4f64(a1, b0, acc[1][0], 0, 0, 0);
            acc[1][1] = __builtin_amdgcn_mfma_f64_16x16x4f64(a1, b1, acc[1][1], 0, 0, 0);
        }
        buf ^= 1;
    }

    #pragma unroll
    for (int ot = 0; ot < 2; ++ot)
        #pragma unroll
        for (int nt = 0; nt < 2; ++nt)
            #pragma unroll
            for (int r = 0; r < 4; ++r)
                H[(size_t)(o0 + ow + ot * 16 + rowv[r]) * N + (n0 + nw + nt * 16 + colv[r])] =
                    acc[ot][nt][r];
}

// ---------------------------------------------------------------------------
// Proj GEMM: 32(o) x 64(n) block tile -> grid (16, 8, 4) = 512 blocks
// (2 blocks/CU; the old 64x64 tiling gave only 256 blocks = 1 wave/SIMD,
// starving the MFMA pipe). 4 waves of 16x32 (1x2 accs). K-chunk 32, dbuf.
// ---------------------------------------------------------------------------
__global__ __launch_bounds__(256) void gemm_p_mfma(
    const float* __restrict__ Wp, const unsigned char* __restrict__ s2,
    double* __restrict__ hp)
{
    const int m = blockIdx.z;
    const unsigned char* __restrict__ X = s2 + (size_t)m * C * N;
    double* __restrict__ H = hp + (size_t)m * C * N;

    const int n0 = blockIdx.x * 64;
    const int o0 = blockIdx.y * 32;
    const int tid  = threadIdx.x;
    const int lane = tid & 63;
    const int w    = tid >> 6;
    const int ow   = (w & 1) * 16;       // wave o offset (16 rows)
    const int nw   = (w >> 1) * 32;      // wave n offset (32 cols)
    const int lm   = lane & 15;
    const int lk   = lane >> 4;

    int rowv[4], colv[4];
    probe_d_layout(lane, rowv, colv);

    __shared__ __align__(16) float As[2][32 * ASTR];   // 32o x 32k
    __shared__ __align__(16) float Bs[2][32 * BSTR];   // 32k x 64n

    d4 acc[2];
    acc[0] = (d4){0.0, 0.0, 0.0, 0.0};
    acc[1] = (d4){0.0, 0.0, 0.0, 0.0};

    const int rA = tid >> 3;             // 0..31
    const int cA = (tid & 7) * 4;        // 0..28
    const int rB = tid >> 3;             // 0..31
    const int cB = (tid & 7) * 8;        // 0..56

    float4 ar;
    uint2 bw;
    ar = *(const float4*)(Wp + (size_t)(o0 + rA) * C + 0 + cA);
    bw = *(const uint2*)(X + (size_t)(0 + rB) * N + n0 + cB);

    int buf = 0;
    for (int ch = 0; ch < 8; ++ch) {
        *(float4*)(&As[buf][rA * ASTR + cA]) = ar;
        float* bs = &Bs[buf][rB * BSTR + cB];
        bs[0] = (float)(bw.x & 0xFF);
        bs[1] = (float)((bw.x >> 8) & 0xFF);
        bs[2] = (float)((bw.x >> 16) & 0xFF);
        bs[3] = (float)((bw.x >> 24) & 0xFF);
        bs[4] = (float)(bw.y & 0xFF);
        bs[5] = (float)((bw.y >> 8) & 0xFF);
        bs[6] = (float)((bw.y >> 16) & 0xFF);
        bs[7] = (float)((bw.y >> 24) & 0xFF);
        __syncthreads();
        if (ch < 7) {
            const int c0 = (ch + 1) * 32;
            ar = *(const float4*)(Wp + (size_t)(o0 + rA) * C + c0 + cA);
            bw = *(const uint2*)(X + (size_t)(c0 + rB) * N + n0 + cB);
        }
        const float* __restrict__ Ab = As[buf];
        const float* __restrict__ Bb = Bs[buf];
        #pragma unroll
        for (int ks = 0; ks < 8; ++ks) {
            const int kk = ks * 4 + lk;
            double a0 = (double)Ab[(ow + lm) * ASTR + kk];
            double b0 = (double)Bb[kk * BSTR + nw + lm];
            double b1 = (double)Bb[kk * BSTR + nw + 16 + lm];
            acc[0] = __builtin_amdgcn_mfma_f64_16x16x4f64(a0, b0, acc[0], 0, 0, 0);
            acc[1] = __builtin_amdgcn_mfma_f64_16x16x4f64(a0, b1, acc[1], 0, 0, 0);
        }
        buf ^= 1;
    }

    #pragma unroll
    for (int nt = 0; nt < 2; ++nt)
        #pragma unroll
        for (int r = 0; r < 4; ++r)
            H[(size_t)(o0 + ow + rowv[r]) * N + (n0 + nw + nt * 16 + colv[r])] =
                acc[nt][r];
}

// ---------------------------------------------------------------------------
// Fused BN stats + spike for q/k/v. Block = (channel o, branch br).
// double2 loads / uchar2 stores (nn even -> aligned).
// ---------------------------------------------------------------------------
__global__ __launch_bounds__(256) void bnspike_qkv(
    const double* __restrict__ hbase,
    const float* __restrict__ gq, const float* __restrict__ bq,
    const float* __restrict__ gk, const float* __restrict__ bk,
    const float* __restrict__ gv, const float* __restrict__ bv,
    unsigned char* __restrict__ sbase)
{
    const int o  = blockIdx.x;
    const int br = blockIdx.y;
    const double* __restrict__ h = hbase + (size_t)br * PLANE + (size_t)o * N;
    const int tid = threadIdx.x;

    double2 v[8];
    double s = 0.0, ss = 0.0;
    #pragma unroll
    for (int j = 0; j < 8; ++j) {
        int idx = j * 512 + tid * 2;        // 0..4094, even
        int mm = idx >> 10, nn = idx & 1023;
        v[j] = *(const double2*)(h + (size_t)mm * C * N + nn);
        s  += v[j].x + v[j].y;
        ss += v[j].x * v[j].x + v[j].y * v[j].y;
    }
    #pragma unroll
    for (int off = 32; off > 0; off >>= 1) {
        s  += __shfl_down(s, off, 64);
        ss += __shfl_down(ss, off, 64);
    }
    __shared__ double rs[4], rss[4], sstat[2];
    const int lane = tid & 63, wv_ = tid >> 6;
    if (lane == 0) { rs[wv_] = s; rss[wv_] = ss; }
    __syncthreads();
    if (tid == 0) {
        double S  = rs[0] + rs[1] + rs[2] + rs[3];
        double SS = rss[0] + rss[1] + rss[2] + rss[3];
        double mean = S / 4096.0;
        double var  = SS / 4096.0 - mean * mean;
        sstat[0] = mean;
        sstat[1] = 1.0 / sqrt(var + 1e-5);
    }
    __syncthreads();
    const double mean = sstat[0], inv = sstat[1];
    const float* g = (br == 0) ? gq : (br == 1) ? gk : gv;
    const float* b = (br == 0) ? bq : (br == 1) ? bk : bv;
    const double gc = (double)g[o], bc = (double)b[o];
    unsigned char* out = sbase + (size_t)br * PLANE + (size_t)o * N;
    #pragma unroll
    for (int j = 0; j < 8; ++j) {
        int idx = j * 512 + tid * 2;
        int mm = idx >> 10, nn = idx & 1023;
        double t0 = gc * (v[j].x - mean) * inv + bc;
        double t1 = gc * (v[j].y - mean) * inv + bc;
        unsigned short pk = (unsigned short)((t0 >= 1.0) ? 1u : 0u) |
                            (unsigned short)(((t1 >= 1.0) ? 1u : 0u) << 8);
        *(unsigned short*)(out + (size_t)mm * C * N + nn) = pk;
    }
}

// ---------------------------------------------------------------------------
// Fused attention: kTv (popc over packed 0/1 bytes) + S = q . kTv, spike S>=2
// (== SCALE*S >= 0.5 with exact integers). grid = (4 n-chunks, 16 heads, 4 t).
// ---------------------------------------------------------------------------
__global__ __launch_bounds__(256) void attn_kernel(
    const unsigned char* __restrict__ qb, const unsigned char* __restrict__ kb,
    const unsigned char* __restrict__ vb, unsigned char* __restrict__ s2)
{
    const int nc = blockIdx.x;
    const int hh = blockIdx.y;
    const int t  = blockIdx.z;
    const int tid = threadIdx.x;

    __shared__ unsigned int kw[16][257];
    __shared__ unsigned int vw[16][257];
    __shared__ int kt[256];

    #pragma unroll
    for (int j = 0; j < 4; ++j) {
        int idx = j * 256 + tid;            // 0..1023 -> 16 rows x 64 uint4
        int r = idx >> 6, q4 = idx & 63;
        size_t goff = ((size_t)(t * C + hh * 16 + r)) * N + (size_t)q4 * 16;
        uint4 kk = *(const uint4*)(kb + goff);
        uint4 vv = *(const uint4*)(vb + goff);
        kw[r][q4 * 4 + 0] = kk.x; kw[r][q4 * 4 + 1] = kk.y;
        kw[r][q4 * 4 + 2] = kk.z; kw[r][q4 * 4 + 3] = kk.w;
        vw[r][q4 * 4 + 0] = vv.x; vw[r][q4 * 4 + 1] = vv.y;
        vw[r][q4 * 4 + 2] = vv.z; vw[r][q4 * 4 + 3] = vv.w;
    }
    __syncthreads();

    const int d = tid >> 4, dp = tid & 15;
    int sum = 0;
    #pragma unroll 8
    for (int wd = 0; wd < 256; ++wd)
        sum += __popc(kw[d][wd] & vw[dp][wd]);
    kt[tid] = sum;                          // kt[d*16+dp], exact integer
    __syncthreads();

    const int n = nc * 256 + tid;
    int sums[16];
    #pragma unroll
    for (int i = 0; i < 16; ++i) sums[i] = 0;
    #pragma unroll
    for (int d2 = 0; d2 < 16; ++d2) {
        int qv = (int)qb[((size_t)(t * C + hh * 16 + d2)) * N + n];
        #pragma unroll
        for (int dp2 = 0; dp2 < 16; ++dp2)
            sums[dp2] += qv * kt[d2 * 16 + dp2];
    }
    #pragma unroll
    for (int dp2 = 0; dp2 < 16; ++dp2)
        s2[((size_t)(t * C + hh * 16 + dp2)) * N + n] = (sums[dp2] >= 2) ? 1 : 0;
}

// ---------------------------------------------------------------------------
// Fused BN stats + spike for proj -> fp32 0/1 output. grid = (256)
// double2 loads / float2 stores.
// ---------------------------------------------------------------------------
__global__ __launch_bounds__(256) void bnspike_p(
    const double* __restrict__ hp,
    const float* __restrict__ gp, const float* __restrict__ bp,
    float* __restrict__ outp)
{
    const int o = blockIdx.x;
    const double* __restrict__ h = hp + (size_t)o * N;
    const int tid = threadIdx.x;

    double2 v[8];
    double s = 0.0, ss = 0.0;
    #pragma unroll
    for (int j = 0; j < 8; ++j) {
        int idx = j * 512 + tid * 2;
        int mm = idx >> 10, nn = idx & 1023;
        v[j] = *(const double2*)(h + (size_t)mm * C * N + nn);
        s  += v[j].x + v[j].y;
        ss += v[j].x * v[j].x + v[j].y * v[j].y;
    }
    #pragma unroll
    for (int off = 32; off > 0; off >>= 1) {
        s  += __shfl_down(s, off, 64);
        ss += __shfl_down(ss, off, 64);
    }
    __shared__ double rs[4], rss[4], sstat[2];
    const int lane = tid & 63, wv_ = tid >> 6;
    if (lane == 0) { rs[wv_] = s; rss[wv_] = ss; }
    __syncthreads();
    if (tid == 0) {
        double S  = rs[0] + rs[1] + rs[2] + rs[3];
        double SS = rss[0] + rss[1] + rss[2] + rss[3];
        double mean = S / 4096.0;
        double var  = SS / 4096.0 - mean * mean;
        sstat[0] = mean;
        sstat[1] = 1.0 / sqrt(var + 1e-5);
    }
    __syncthreads();
    const double mean = sstat[0], inv = sstat[1];
    const double gc = (double)gp[o], bc = (double)bp[o];
    float* out = outp + (size_t)o * N;
    #pragma unroll
    for (int j = 0; j < 8; ++j) {
        int idx = j * 512 + tid * 2;
        int mm = idx >> 10, nn = idx & 1023;
        float2 r;
        r.x = (gc * (v[j].x - mean) * inv + bc >= 1.0) ? 1.0f : 0.0f;
        r.y = (gc * (v[j].y - mean) * inv + bc >= 1.0) ? 1.0f : 0.0f;
        *(float2*)(out + (size_t)mm * C * N + nn) = r;
    }
}

// ---------------------------------------------------------------------------
extern "C" void kernel_launch(void* const* d_in, const int* in_sizes, int n_in,
                              void* d_out, int out_size, void* d_ws, size_t ws_size,
                              hipStream_t stream)
{
    const float* x  = (const float*)d_in[0];
    const float* y  = (const float*)d_in[1];
    const float* Wq = (const float*)d_in[2];
    const float* gq = (const float*)d_in[3];
    const float* bq = (const float*)d_in[4];
    const float* Wk = (const float*)d_in[5];
    const float* gk = (const float*)d_in[6];
    const float* bk = (const float*)d_in[7];
    const float* Wv = (const float*)d_in[8];
    const float* gv = (const float*)d_in[9];
    const float* bv = (const float*)d_in[10];
    const float* Wp = (const float*)d_in[11];
    const float* gp = (const float*)d_in[12];
    const float* bp = (const float*)d_in[13];
    float* out = (float*)d_out;

    // Workspace layout (28 MB):
    //   [0, 24MB)  hq (3 branches fp64); hp (4 planes fp64) aliases [0,8MB)
    //   [24, 28MB) qb/kb/vb/s2b binary bytes
    char* ws = (char*)d_ws;
    double* hq = (double*)ws;
    double* hp = hq;                                      // alias: hq dead by then
    unsigned char* qb  = (unsigned char*)(ws + 3 * PLANE * sizeof(double));
    unsigned char* kb2 = qb + PLANE;
    unsigned char* vb2 = qb + 2 * PLANE;
    unsigned char* s2b = qb + 3 * PLANE;

    gemm_qkv_mfma<<<dim3(16, 4, 12), 256, 0, stream>>>(x, y, Wq, Wk, Wv, hq);
    bnspike_qkv<<<dim3(256, 3), 256, 0, stream>>>(hq, gq, bq, gk, bk, gv, bv, qb);
    attn_kernel<<<dim3(4, 16, 4), 256, 0, stream>>>(qb, kb2, vb2, s2b);
    gemm_p_mfma<<<dim3(16, 8, 4), 256, 0, stream>>>(Wp, s2b, hp);
    bnspike_p<<<dim3(256), 256, 0, stream>>>(hp, gp, bp, out);
}

// Round 10
// 147.780 us; speedup vs baseline: 1.2683x; 1.0045x over previous
//
#include <hip/hip_runtime.h>
#include <cstdint>
#include <cstddef>

static constexpr int C = 256;
static constexpr int N = 1024;
static constexpr int M = 4;                         // T*B
static constexpr size_t PLANE = (size_t)M * C * N;  // 1M elements per branch

typedef double d4 __attribute__((ext_vector_type(4)));

// Runtime-probe the C/D register->(row,col) mapping of v_mfma_f64_16x16x4.
// Input layout A[m=lane&15][k=lane>>4], B[k=lane>>4][n=lane&15] (verified:
// R6/R7/R8 pass with absmax 0).
__device__ inline void probe_d_layout(int lane, int rowv[4], int colv[4])
{
    const double am = (lane < 16) ? (double)lane : 0.0;
    const double a1 = (lane < 16) ? 1.0 : 0.0;
    const double bn = (lane < 16) ? (double)(lane & 15) : 0.0;
    d4 z = (d4){0.0, 0.0, 0.0, 0.0};
    d4 dr = __builtin_amdgcn_mfma_f64_16x16x4f64(am, a1, z, 0, 0, 0);
    d4 dc = __builtin_amdgcn_mfma_f64_16x16x4f64(a1, bn, z, 0, 0, 0);
    #pragma unroll
    for (int r = 0; r < 4; ++r) {
        rowv[r] = (int)dr[r];
        colv[r] = (int)dc[r];
    }
}

static constexpr int ASTR = 36;   // A[o][k] lds stride (floats): <=2-way banks
static constexpr int BSTR = 72;   // B[k][n] lds stride

// ---------------------------------------------------------------------------
// fp64 MFMA GEMM: H[m][o][n] = sum_c W[o][c] * X[m][c][n]
// Block tile 64(o) x 64(n), 4 waves of 32x32 (2x2 16x16 accs).
// K-chunk 32, double-buffered fp32 LDS staging, ONE barrier per chunk.
// grid = (16 n-tiles, 4 o-tiles, 12 planes[br*4+m])
// ---------------------------------------------------------------------------
__global__ __launch_bounds__(256) void gemm_qkv_mfma(
    const float* __restrict__ x, const float* __restrict__ y,
    const float* __restrict__ Wq, const float* __restrict__ Wk,
    const float* __restrict__ Wv, double* __restrict__ hbase)
{
    const int bz = blockIdx.z;           // 0..11
    const int br = bz >> 2;              // 0=q,1=k,2=v
    const int m  = bz & 3;
    const float* __restrict__ W = (br == 0) ? Wq : (br == 1) ? Wk : Wv;
    const float* __restrict__ X = ((br == 0) ? x : y) + (size_t)m * C * N;
    double* __restrict__ H = hbase + (size_t)br * PLANE + (size_t)m * C * N;

    const int n0 = blockIdx.x * 64;
    const int o0 = blockIdx.y * 64;
    const int tid  = threadIdx.x;
    const int lane = tid & 63;
    const int w    = tid >> 6;           // wave id 0..3
    const int ow   = (w & 1) * 32;
    const int nw   = (w >> 1) * 32;
    const int lm   = lane & 15;
    const int lk   = lane >> 4;

    int rowv[4], colv[4];
    probe_d_layout(lane, rowv, colv);

    __shared__ __align__(16) float As[2][64 * ASTR];
    __shared__ __align__(16) float Bs[2][32 * BSTR];

    d4 acc[2][2];
    #pragma unroll
    for (int i = 0; i < 2; ++i)
        #pragma unroll
        for (int j = 0; j < 2; ++j)
            acc[i][j] = (d4){0.0, 0.0, 0.0, 0.0};

    const int rA = tid >> 2;             // 0..63
    const int cA = (tid & 3) * 8;        // 0,8,16,24
    const int rB = tid >> 3;             // 0..31
    const int cB = (tid & 7) * 8;        // 0..56

    float4 a0r, a1r, b0r, b1r;
    a0r = *(const float4*)(W + (size_t)(o0 + rA) * C + 0 + cA);
    a1r = *(const float4*)(W + (size_t)(o0 + rA) * C + 0 + cA + 4);
    b0r = *(const float4*)(X + (size_t)(0 + rB) * N + n0 + cB);
    b1r = *(const float4*)(X + (size_t)(0 + rB) * N + n0 + cB + 4);

    int buf = 0;
    for (int ch = 0; ch < 8; ++ch) {
        *(float4*)(&As[buf][rA * ASTR + cA])     = a0r;
        *(float4*)(&As[buf][rA * ASTR + cA + 4]) = a1r;
        *(float4*)(&Bs[buf][rB * BSTR + cB])     = b0r;
        *(float4*)(&Bs[buf][rB * BSTR + cB + 4]) = b1r;
        __syncthreads();
        if (ch < 7) {
            const int c0 = (ch + 1) * 32;
            a0r = *(const float4*)(W + (size_t)(o0 + rA) * C + c0 + cA);
            a1r = *(const float4*)(W + (size_t)(o0 + rA) * C + c0 + cA + 4);
            b0r = *(const float4*)(X + (size_t)(c0 + rB) * N + n0 + cB);
            b1r = *(const float4*)(X + (size_t)(c0 + rB) * N + n0 + cB + 4);
        }
        const float* __restrict__ Ab = As[buf];
        const float* __restrict__ Bb = Bs[buf];
        #pragma unroll
        for (int ks = 0; ks < 8; ++ks) {
            const int kk = ks * 4 + lk;
            double a0 = (double)Ab[(ow + lm) * ASTR + kk];
            double a1 = (double)Ab[(ow + 16 + lm) * ASTR + kk];
            double b0 = (double)Bb[kk * BSTR + nw + lm];
            double b1 = (double)Bb[kk * BSTR + nw + 16 + lm];
            acc[0][0] = __builtin_amdgcn_mfma_f64_16x16x4f64(a0, b0, acc[0][0], 0, 0, 0);
            acc[0][1] = __builtin_amdgcn_mfma_f64_16x16x4f64(a0, b1, acc[0][1], 0, 0, 0);
            acc[1][0] = __builtin_amdgcn_mfma_f64_16x16x4f64(a1, b0, acc[1][0], 0, 0, 0);
            acc[1][1] = __builtin_amdgcn_mfma_f64_16x16x4f64(a1, b1, acc[1][1], 0, 0, 0);
        }
        buf ^= 1;
    }

    #pragma unroll
    for (int ot = 0; ot < 2; ++ot)
        #pragma unroll
        for (int nt = 0; nt < 2; ++nt)
            #pragma unroll
            for (int r = 0; r < 4; ++r)
                H[(size_t)(o0 + ow + ot * 16 + rowv[r]) * N + (n0 + nw + nt * 16 + colv[r])] =
                    acc[ot][nt][r];
}

// ---------------------------------------------------------------------------
// Proj GEMM: 32(o) x 64(n) block tile -> grid (16, 8, 4) = 512 blocks
// (2 blocks/CU). 4 waves of 16x32 (1x2 accs). K-chunk 32, dbuf.
// ---------------------------------------------------------------------------
__global__ __launch_bounds__(256) void gemm_p_mfma(
    const float* __restrict__ Wp, const unsigned char* __restrict__ s2,
    double* __restrict__ hp)
{
    const int m = blockIdx.z;
    const unsigned char* __restrict__ X = s2 + (size_t)m * C * N;
    double* __restrict__ H = hp + (size_t)m * C * N;

    const int n0 = blockIdx.x * 64;
    const int o0 = blockIdx.y * 32;
    const int tid  = threadIdx.x;
    const int lane = tid & 63;
    const int w    = tid >> 6;
    const int ow   = (w & 1) * 16;       // wave o offset (16 rows)
    const int nw   = (w >> 1) * 32;      // wave n offset (32 cols)
    const int lm   = lane & 15;
    const int lk   = lane >> 4;

    int rowv[4], colv[4];
    probe_d_layout(lane, rowv, colv);

    __shared__ __align__(16) float As[2][32 * ASTR];   // 32o x 32k
    __shared__ __align__(16) float Bs[2][32 * BSTR];   // 32k x 64n

    d4 acc[2];
    acc[0] = (d4){0.0, 0.0, 0.0, 0.0};
    acc[1] = (d4){0.0, 0.0, 0.0, 0.0};

    const int rA = tid >> 3;             // 0..31
    const int cA = (tid & 7) * 4;        // 0..28
    const int rB = tid >> 3;             // 0..31
    const int cB = (tid & 7) * 8;        // 0..56

    float4 ar;
    uint2 bw;
    ar = *(const float4*)(Wp + (size_t)(o0 + rA) * C + 0 + cA);
    bw = *(const uint2*)(X + (size_t)(0 + rB) * N + n0 + cB);

    int buf = 0;
    for (int ch = 0; ch < 8; ++ch) {
        *(float4*)(&As[buf][rA * ASTR + cA]) = ar;
        float* bs = &Bs[buf][rB * BSTR + cB];
        bs[0] = (float)(bw.x & 0xFF);
        bs[1] = (float)((bw.x >> 8) & 0xFF);
        bs[2] = (float)((bw.x >> 16) & 0xFF);
        bs[3] = (float)((bw.x >> 24) & 0xFF);
        bs[4] = (float)(bw.y & 0xFF);
        bs[5] = (float)((bw.y >> 8) & 0xFF);
        bs[6] = (float)((bw.y >> 16) & 0xFF);
        bs[7] = (float)((bw.y >> 24) & 0xFF);
        __syncthreads();
        if (ch < 7) {
            const int c0 = (ch + 1) * 32;
            ar = *(const float4*)(Wp + (size_t)(o0 + rA) * C + c0 + cA);
            bw = *(const uint2*)(X + (size_t)(c0 + rB) * N + n0 + cB);
        }
        const float* __restrict__ Ab = As[buf];
        const float* __restrict__ Bb = Bs[buf];
        #pragma unroll
        for (int ks = 0; ks < 8; ++ks) {
            const int kk = ks * 4 + lk;
            double a0 = (double)Ab[(ow + lm) * ASTR + kk];
            double b0 = (double)Bb[kk * BSTR + nw + lm];
            double b1 = (double)Bb[kk * BSTR + nw + 16 + lm];
            acc[0] = __builtin_amdgcn_mfma_f64_16x16x4f64(a0, b0, acc[0], 0, 0, 0);
            acc[1] = __builtin_amdgcn_mfma_f64_16x16x4f64(a0, b1, acc[1], 0, 0, 0);
        }
        buf ^= 1;
    }

    #pragma unroll
    for (int nt = 0; nt < 2; ++nt)
        #pragma unroll
        for (int r = 0; r < 4; ++r)
            H[(size_t)(o0 + ow + rowv[r]) * N + (n0 + nw + nt * 16 + colv[r])] =
                acc[nt][r];
}

// ---------------------------------------------------------------------------
// Fused BN stats + spike for q/k/v. Block = (channel o, branch br).
// double2 loads / uchar2 stores (nn even -> aligned).
// ---------------------------------------------------------------------------
__global__ __launch_bounds__(256) void bnspike_qkv(
    const double* __restrict__ hbase,
    const float* __restrict__ gq, const float* __restrict__ bq,
    const float* __restrict__ gk, const float* __restrict__ bk,
    const float* __restrict__ gv, const float* __restrict__ bv,
    unsigned char* __restrict__ sbase)
{
    const int o  = blockIdx.x;
    const int br = blockIdx.y;
    const double* __restrict__ h = hbase + (size_t)br * PLANE + (size_t)o * N;
    const int tid = threadIdx.x;

    double2 v[8];
    double s = 0.0, ss = 0.0;
    #pragma unroll
    for (int j = 0; j < 8; ++j) {
        int idx = j * 512 + tid * 2;        // 0..4094, even
        int mm = idx >> 10, nn = idx & 1023;
        v[j] = *(const double2*)(h + (size_t)mm * C * N + nn);
        s  += v[j].x + v[j].y;
        ss += v[j].x * v[j].x + v[j].y * v[j].y;
    }
    #pragma unroll
    for (int off = 32; off > 0; off >>= 1) {
        s  += __shfl_down(s, off, 64);
        ss += __shfl_down(ss, off, 64);
    }
    __shared__ double rs[4], rss[4], sstat[2];
    const int lane = tid & 63, wv_ = tid >> 6;
    if (lane == 0) { rs[wv_] = s; rss[wv_] = ss; }
    __syncthreads();
    if (tid == 0) {
        double S  = rs[0] + rs[1] + rs[2] + rs[3];
        double SS = rss[0] + rss[1] + rss[2] + rss[3];
        double mean = S / 4096.0;
        double var  = SS / 4096.0 - mean * mean;
        sstat[0] = mean;
        sstat[1] = 1.0 / sqrt(var + 1e-5);
    }
    __syncthreads();
    const double mean = sstat[0], inv = sstat[1];
    const float* g = (br == 0) ? gq : (br == 1) ? gk : gv;
    const float* b = (br == 0) ? bq : (br == 1) ? bk : bv;
    const double gc = (double)g[o], bc = (double)b[o];
    unsigned char* out = sbase + (size_t)br * PLANE + (size_t)o * N;
    #pragma unroll
    for (int j = 0; j < 8; ++j) {
        int idx = j * 512 + tid * 2;
        int mm = idx >> 10, nn = idx & 1023;
        double t0 = gc * (v[j].x - mean) * inv + bc;
        double t1 = gc * (v[j].y - mean) * inv + bc;
        unsigned short pk = (unsigned short)((t0 >= 1.0) ? 1u : 0u) |
                            (unsigned short)(((t1 >= 1.0) ? 1u : 0u) << 8);
        *(unsigned short*)(out + (size_t)mm * C * N + nn) = pk;
    }
}

// ---------------------------------------------------------------------------
// Fused attention: kTv (popc over packed 0/1 bytes) + S = q . kTv, spike S>=2
// (== SCALE*S >= 0.5 with exact integers). grid = (4 n-chunks, 16 heads, 4 t).
// ---------------------------------------------------------------------------
__global__ __launch_bounds__(256) void attn_kernel(
    const unsigned char* __restrict__ qb, const unsigned char* __restrict__ kb,
    const unsigned char* __restrict__ vb, unsigned char* __restrict__ s2)
{
    const int nc = blockIdx.x;
    const int hh = blockIdx.y;
    const int t  = blockIdx.z;
    const int tid = threadIdx.x;

    __shared__ unsigned int kw[16][257];
    __shared__ unsigned int vw[16][257];
    __shared__ int kt[256];

    #pragma unroll
    for (int j = 0; j < 4; ++j) {
        int idx = j * 256 + tid;            // 0..1023 -> 16 rows x 64 uint4
        int r = idx >> 6, q4 = idx & 63;
        size_t goff = ((size_t)(t * C + hh * 16 + r)) * N + (size_t)q4 * 16;
        uint4 kk = *(const uint4*)(kb + goff);
        uint4 vv = *(const uint4*)(vb + goff);
        kw[r][q4 * 4 + 0] = kk.x; kw[r][q4 * 4 + 1] = kk.y;
        kw[r][q4 * 4 + 2] = kk.z; kw[r][q4 * 4 + 3] = kk.w;
        vw[r][q4 * 4 + 0] = vv.x; vw[r][q4 * 4 + 1] = vv.y;
        vw[r][q4 * 4 + 2] = vv.z; vw[r][q4 * 4 + 3] = vv.w;
    }
    __syncthreads();

    const int d = tid >> 4, dp = tid & 15;
    int sum = 0;
    #pragma unroll 8
    for (int wd = 0; wd < 256; ++wd)
        sum += __popc(kw[d][wd] & vw[dp][wd]);
    kt[tid] = sum;                          // kt[d*16+dp], exact integer
    __syncthreads();

    const int n = nc * 256 + tid;
    int sums[16];
    #pragma unroll
    for (int i = 0; i < 16; ++i) sums[i] = 0;
    #pragma unroll
    for (int d2 = 0; d2 < 16; ++d2) {
        int qv = (int)qb[((size_t)(t * C + hh * 16 + d2)) * N + n];
        #pragma unroll
        for (int dp2 = 0; dp2 < 16; ++dp2)
            sums[dp2] += qv * kt[d2 * 16 + dp2];
    }
    #pragma unroll
    for (int dp2 = 0; dp2 < 16; ++dp2)
        s2[((size_t)(t * C + hh * 16 + dp2)) * N + n] = (sums[dp2] >= 2) ? 1 : 0;
}

// ---------------------------------------------------------------------------
// Fused BN stats + spike for proj -> fp32 0/1 output. grid = (256)
// double2 loads / float2 stores.
// ---------------------------------------------------------------------------
__global__ __launch_bounds__(256) void bnspike_p(
    const double* __restrict__ hp,
    const float* __restrict__ gp, const float* __restrict__ bp,
    float* __restrict__ outp)
{
    const int o = blockIdx.x;
    const double* __restrict__ h = hp + (size_t)o * N;
    const int tid = threadIdx.x;

    double2 v[8];
    double s = 0.0, ss = 0.0;
    #pragma unroll
    for (int j = 0; j < 8; ++j) {
        int idx = j * 512 + tid * 2;
        int mm = idx >> 10, nn = idx & 1023;
        v[j] = *(const double2*)(h + (size_t)mm * C * N + nn);
        s  += v[j].x + v[j].y;
        ss += v[j].x * v[j].x + v[j].y * v[j].y;
    }
    #pragma unroll
    for (int off = 32; off > 0; off >>= 1) {
        s  += __shfl_down(s, off, 64);
        ss += __shfl_down(ss, off, 64);
    }
    __shared__ double rs[4], rss[4], sstat[2];
    const int lane = tid & 63, wv_ = tid >> 6;
    if (lane == 0) { rs[wv_] = s; rss[wv_] = ss; }
    __syncthreads();
    if (tid == 0) {
        double S  = rs[0] + rs[1] + rs[2] + rs[3];
        double SS = rss[0] + rss[1] + rss[2] + rss[3];
        double mean = S / 4096.0;
        double var  = SS / 4096.0 - mean * mean;
        sstat[0] = mean;
        sstat[1] = 1.0 / sqrt(var + 1e-5);
    }
    __syncthreads();
    const double mean = sstat[0], inv = sstat[1];
    const double gc = (double)gp[o], bc = (double)bp[o];
    float* out = outp + (size_t)o * N;
    #pragma unroll
    for (int j = 0; j < 8; ++j) {
        int idx = j * 512 + tid * 2;
        int mm = idx >> 10, nn = idx & 1023;
        float2 r;
        r.x = (gc * (v[j].x - mean) * inv + bc >= 1.0) ? 1.0f : 0.0f;
        r.y = (gc * (v[j].y - mean) * inv + bc >= 1.0) ? 1.0f : 0.0f;
        *(float2*)(out + (size_t)mm * C * N + nn) = r;
    }
}

// ---------------------------------------------------------------------------
extern "C" void kernel_launch(void* const* d_in, const int* in_sizes, int n_in,
                              void* d_out, int out_size, void* d_ws, size_t ws_size,
                              hipStream_t stream)
{
    const float* x  = (const float*)d_in[0];
    const float* y  = (const float*)d_in[1];
    const float* Wq = (const float*)d_in[2];
    const float* gq = (const float*)d_in[3];
    const float* bq = (const float*)d_in[4];
    const float* Wk = (const float*)d_in[5];
    const float* gk = (const float*)d_in[6];
    const float* bk = (const float*)d_in[7];
    const float* Wv = (const float*)d_in[8];
    const float* gv = (const float*)d_in[9];
    const float* bv = (const float*)d_in[10];
    const float* Wp = (const float*)d_in[11];
    const float* gp = (const float*)d_in[12];
    const float* bp = (const float*)d_in[13];
    float* out = (float*)d_out;

    // Workspace layout (28 MB):
    //   [0, 24MB)  hq (3 branches fp64); hp (4 planes fp64) aliases [0,8MB)
    //   [24, 28MB) qb/kb/vb/s2b binary bytes
    char* ws = (char*)d_ws;
    double* hq = (double*)ws;
    double* hp = hq;                                      // alias: hq dead by then
    unsigned char* qb  = (unsigned char*)(ws + 3 * PLANE * sizeof(double));
    unsigned char* kb2 = qb + PLANE;
    unsigned char* vb2 = qb + 2 * PLANE;
    unsigned char* s2b = qb + 3 * PLANE;

    gemm_qkv_mfma<<<dim3(16, 4, 12), 256, 0, stream>>>(x, y, Wq, Wk, Wv, hq);
    bnspike_qkv<<<dim3(256, 3), 256, 0, stream>>>(hq, gq, bq, gk, bk, gv, bv, qb);
    attn_kernel<<<dim3(4, 16, 4), 256, 0, stream>>>(qb, kb2, vb2, s2b);
    gemm_p_mfma<<<dim3(16, 8, 4), 256, 0, stream>>>(Wp, s2b, hp);
    bnspike_p<<<dim3(256), 256, 0, stream>>>(hp, gp, bp, out);
}